// Round 12
// baseline (234.059 us; speedup 1.0000x reference)
//
#include <hip/hip_runtime.h>
#include <math.h>

#define F_IN 256
#define H1 8
#define C1 128
#define HC1 1024
#define C2 128
#define SLOPE 0.2f

typedef unsigned short u16;
typedef __attribute__((ext_vector_type(8))) short bf16x8;
typedef __attribute__((ext_vector_type(4))) float f32x4;

// ---------------- helpers ----------------

__device__ __forceinline__ float lrelu(float v) { return v > 0.f ? v : SLOPE * v; }

__device__ __forceinline__ unsigned bf16_rne(float x) {
    unsigned u = __float_as_uint(x);
    u += 0x7fffu + ((u >> 16) & 1u);
    return u >> 16;
}

// split a,b into packed-bf16 hi pair and lo pair (lo = exact residual, rounded)
__device__ __forceinline__ void split2(float a, float b, unsigned& hi, unsigned& lo) {
    unsigned ha = bf16_rne(a), hb = bf16_rne(b);
    float fa = __uint_as_float(ha << 16), fb = __uint_as_float(hb << 16);
    hi = ha | (hb << 16);
    lo = bf16_rne(a - fa) | (bf16_rne(b - fb) << 16);
}

__device__ __forceinline__ void gload16(const u16* g, u16* l) {
    __builtin_amdgcn_global_load_lds(
        (const __attribute__((address_space(1))) unsigned*)g,
        (__attribute__((address_space(3))) unsigned*)l, 16, 0, 0);
}

// ---------------- edge sorting (counting sort by dst) ----------------

__global__ void hist_kernel(const int* __restrict__ dst, int* __restrict__ deg, int E) {
    int i = blockIdx.x * blockDim.x + threadIdx.x;
    if (i < E) atomicAdd(&deg[dst[i]], 1);
}

// wave-shuffle two-level scan: 3 barriers/chunk (was 20)
__global__ void scan_kernel(const int* __restrict__ deg, int* __restrict__ start,
                            int* __restrict__ cursor, int n) {
    __shared__ int wsum[16];
    __shared__ int wpre[16];
    __shared__ int ctot;
    const int tid = threadIdx.x;
    const int lane = tid & 63, wv = tid >> 6;
    int carry = 0;
    for (int base = 0; base < n; base += 1024) {
        int i = base + tid;
        int v = (i < n) ? deg[i] : 0;
        int x = v;  // inclusive wave scan
#pragma unroll
        for (int o = 1; o < 64; o <<= 1) {
            int y = __shfl_up(x, o);
            if (lane >= o) x += y;
        }
        if (lane == 63) wsum[wv] = x;
        __syncthreads();
        if (tid < 16) {
            int s = wsum[tid];
            int xx = s;
#pragma unroll
            for (int o = 1; o < 16; o <<= 1) {
                int y = __shfl_up(xx, o);
                if (tid >= o) xx += y;
            }
            wpre[tid] = xx - s;        // exclusive prefix of wave sums
            if (tid == 15) ctot = xx;  // chunk total
        }
        __syncthreads();
        int excl = carry + wpre[wv] + (x - v);
        if (i < n) { start[i] = excl; cursor[i] = excl; }
        carry += ctot;
        __syncthreads();  // protect wsum/wpre/ctot for next chunk
    }
    if (tid == 0) start[n] = carry;
}

__global__ void scatter_kernel(const int* __restrict__ src, const int* __restrict__ dst,
                               int* __restrict__ cursor, int* __restrict__ ssorted,
                               unsigned char* __restrict__ rowloc,
                               int E, int N) {
    int i = blockIdx.x * blockDim.x + threadIdx.x;
    if (i < E) {
        int d = dst[i];
        int pos = atomicAdd(&cursor[d], 1);
        ssorted[pos] = src[i];
        rowloc[pos] = (unsigned char)(d & 15);
    } else if (i < E + N) {
        int d = i - E;
        int pos = atomicAdd(&cursor[d], 1);
        ssorted[pos] = d;
        rowloc[pos] = (unsigned char)(d & 15);
    }
}

// ---------------- fp32 -> bf16 hi/lo split ----------------

// split x + init deg=1 (self-loop) in one pass; runs BEFORE hist_kernel
__global__ void split_mat_deg(const float* __restrict__ in, u16* __restrict__ hi,
                              u16* __restrict__ lo, int n,
                              int* __restrict__ deg, int nd) {
    int i = blockIdx.x * blockDim.x + threadIdx.x;
    if (i < nd) deg[i] = 1;
    if (i >= n) return;
    float v = in[i];
    unsigned h = bf16_rne(v);
    hi[i] = (u16)h;
    lo[i] = (u16)bf16_rne(v - __uint_as_float(h << 16));
}

// two transposed splits in one launch (ranges) + zero ss2/sd2 (for the
// atomicAdd-based fused layer-2 scores; runs strictly before gemm_mfma64)
__global__ void split_transpose2(const float* __restrict__ in1, u16* __restrict__ hi1,
                                 u16* __restrict__ lo1, int R1, int Cc1,
                                 const float* __restrict__ in2, u16* __restrict__ hi2,
                                 u16* __restrict__ lo2, int R2, int Cc2,
                                 float* __restrict__ z1, float* __restrict__ z2,
                                 int nz) {
    int i = blockIdx.x * blockDim.x + threadIdx.x;
    if (i < nz) { z1[i] = 0.f; z2[i] = 0.f; }
    int n1 = R1 * Cc1;
    if (i < n1) {
        int r = i / Cc1, c = i % Cc1;
        float v = in1[i];
        unsigned h = bf16_rne(v);
        hi1[(size_t)c * R1 + r] = (u16)h;
        lo1[(size_t)c * R1 + r] = (u16)bf16_rne(v - __uint_as_float(h << 16));
    } else {
        int j = i - n1;
        if (j >= R2 * Cc2) return;
        int r = j / Cc2, c = j % Cc2;
        float v = in2[j];
        unsigned h = bf16_rne(v);
        hi2[(size_t)c * R2 + r] = (u16)h;
        lo2[(size_t)c * R2 + r] = (u16)bf16_rne(v - __uint_as_float(h << 16));
    }
}

// ---------------- split-bf16 MFMA GEMM, 128x128 tile, fused scores ----------
// C[M,N](bf16) = (Ahi+Alo)[M,K] @ (Bhi+Blo)^T[N,K], fp32 accumulate.
// Layer-1 only: col tile 128 = exactly one head -> the block computes that
// head's s_src/s_dst for its 128 rows in the epilogue (fp32 acc, lrow
// butterfly + 2KB LDS cross-wave combine). Replaces the scores1_bf kernel.

__global__ __launch_bounds__(256) void gemm_mfma(const u16* __restrict__ Ahi,
                                                 const u16* __restrict__ Alo,
                                                 const u16* __restrict__ Bhi,
                                                 const u16* __restrict__ Blo,
                                                 u16* __restrict__ Cbf,
                                                 int M, int N, int K,
                                                 const float* __restrict__ a_s,
                                                 const float* __restrict__ a_d,
                                                 float* __restrict__ ssrc,
                                                 float* __restrict__ sdst) {
    __shared__ u16 lds[16384];  // 4 tiles x [128][32] bf16 = 32 KB
    const int t = threadIdx.x;
    const int rbase = blockIdx.y * 128;
    const int cbase = blockIdx.x * 128;

    const int lane = t & 63;
    const int R0 = (t >> 7) << 6;
    const int C0 = ((t >> 6) & 1) << 6;
    const int lrow = lane & 15;
    const int kq = lane >> 4;

    f32x4 acc[4][4] = {};

    for (int k0 = 0; k0 < K; k0 += 32) {
#pragma unroll
        for (int i = 0; i < 2; i++) {
            int c = t + (i << 8);
            int row = c >> 2;
            int kc = (c & 3) << 3;
            int ar = min(rbase + row, M - 1);
            int br = cbase + row;
            gload16(Ahi + (size_t)ar * K + k0 + kc, &lds[c * 8]);
            gload16(Alo + (size_t)ar * K + k0 + kc, &lds[4096 + c * 8]);
            gload16(Bhi + (size_t)br * K + k0 + kc, &lds[8192 + c * 8]);
            gload16(Blo + (size_t)br * K + k0 + kc, &lds[12288 + c * 8]);
        }
        __syncthreads();

        bf16x8 ah[4], al[4], bh[4], bl[4];
#pragma unroll
        for (int m = 0; m < 4; m++) {
            int off = (R0 + (m << 4) + lrow) * 32 + (kq << 3);
            ah[m] = *(const bf16x8*)&lds[off];
            al[m] = *(const bf16x8*)&lds[4096 + off];
        }
#pragma unroll
        for (int n = 0; n < 4; n++) {
            int off = (C0 + (n << 4) + lrow) * 32 + (kq << 3);
            bh[n] = *(const bf16x8*)&lds[8192 + off];
            bl[n] = *(const bf16x8*)&lds[12288 + off];
        }
#pragma unroll
        for (int m = 0; m < 4; m++)
#pragma unroll
            for (int n = 0; n < 4; n++) {
                acc[m][n] = __builtin_amdgcn_mfma_f32_16x16x32_bf16(ah[m], bh[n], acc[m][n], 0, 0, 0);
                acc[m][n] = __builtin_amdgcn_mfma_f32_16x16x32_bf16(ah[m], bl[n], acc[m][n], 0, 0, 0);
                acc[m][n] = __builtin_amdgcn_mfma_f32_16x16x32_bf16(al[m], bh[n], acc[m][n], 0, 0, 0);
            }
        __syncthreads();
    }

    // C store
#pragma unroll
    for (int m = 0; m < 4; m++)
#pragma unroll
        for (int n = 0; n < 4; n++) {
            int col = cbase + C0 + (n << 4) + lrow;
#pragma unroll
            for (int r = 0; r < 4; r++) {
                int row = rbase + R0 + (m << 4) + kq * 4 + r;
                if (row < M) Cbf[(size_t)row * N + col] = (u16)bf16_rne(acc[m][n][r]);
            }
        }

    // fused scores for head = blockIdx.x (staging LDS is free after the loop)
    {
        float* fl = (float*)lds;     // sS = fl[0..255], sD = fl[256..511]
        const int head = blockIdx.x;
        const int c01 = (t >> 6) & 1;
        float asv[4], adv[4];
#pragma unroll
        for (int n = 0; n < 4; n++) {
            int col = head * 128 + C0 + (n << 4) + lrow;
            asv[n] = a_s[col];
            adv[n] = a_d[col];
        }
#pragma unroll
        for (int m = 0; m < 4; m++)
#pragma unroll
            for (int r = 0; r < 4; r++) {
                float vs = 0.f, vd = 0.f;
#pragma unroll
                for (int n = 0; n < 4; n++) {
                    float h = acc[m][n][r];
                    vs += asv[n] * h;
                    vd += adv[n] * h;
                }
#pragma unroll
                for (int o = 1; o < 16; o <<= 1) {  // reduce over lrow (16 lanes)
                    vs += __shfl_xor(vs, o);
                    vd += __shfl_xor(vd, o);
                }
                if (lrow == 0) {
                    int lr = R0 + (m << 4) + kq * 4 + r;
                    fl[c01 * 128 + lr] = vs;
                    fl[256 + c01 * 128 + lr] = vd;
                }
            }
        __syncthreads();
        if (t < 128) {
            int row = rbase + t;
            if (row < M) {
                ssrc[row * H1 + head] = fl[t] + fl[128 + t];
                sdst[row * H1 + head] = fl[256 + t] + fl[384 + t];
            }
        }
    }
}

// ---------------- split-bf16 MFMA GEMM, 64x64 tile, BK=64, fused scores2 ----
// Two [64][32] sub-tiles per operand per iteration -> 16 K-iterations,
// 24 MFMAs per barrier pair.  [verified passing, rounds 6-9]
// Layer-2 scores fused (r8 pattern): per-row partial over this block's 64
// cols from fp32 acc, lrow butterfly + LDS combine, then atomicAdd into
// ss2/sd2 (2 commutative adds onto exact 0 -> deterministic).

__global__ __launch_bounds__(256) void gemm_mfma64(const u16* __restrict__ Ahi,
                                                   const u16* __restrict__ Alo,
                                                   const u16* __restrict__ Bhi,
                                                   const u16* __restrict__ Blo,
                                                   u16* __restrict__ Cbf,
                                                   int M, int N, int K,
                                                   const float* __restrict__ a_s,
                                                   const float* __restrict__ a_d,
                                                   float* __restrict__ ssrc,
                                                   float* __restrict__ sdst) {
    __shared__ u16 lds[16384];  // 4 operands x [2 ksub][64][32] bf16 = 32 KB
    const int t = threadIdx.x;
    const int rbase = blockIdx.y * 64;
    const int cbase = blockIdx.x * 64;

    const int lane = t & 63;
    const int w = t >> 6;
    const int R0 = (w >> 1) << 5;   // 0 / 32
    const int C0 = (w & 1) << 5;    // 0 / 32
    const int lrow = lane & 15;
    const int kq = lane >> 4;

    f32x4 acc[2][2] = {};

    for (int k0 = 0; k0 < K; k0 += 64) {
        {
            int row = (w << 4) + (lane >> 2);
            int kcc = (lane & 3) << 3;
            int ar = min(rbase + row, M - 1);
            int br = cbase + row;
            const size_t ga = (size_t)ar * K + k0 + kcc;
            const size_t gb = (size_t)br * K + k0 + kcc;
            const int ldo = row * 32 + kcc;
#pragma unroll
            for (int s2 = 0; s2 < 2; s2++) {
                gload16(Ahi + ga + s2 * 32, &lds[s2 * 2048 + ldo]);
                gload16(Alo + ga + s2 * 32, &lds[4096 + s2 * 2048 + ldo]);
                gload16(Bhi + gb + s2 * 32, &lds[8192 + s2 * 2048 + ldo]);
                gload16(Blo + gb + s2 * 32, &lds[12288 + s2 * 2048 + ldo]);
            }
        }
        __syncthreads();

#pragma unroll
        for (int s = 0; s < 2; s++) {
            bf16x8 ah[2], al[2], bh[2], bl[2];
#pragma unroll
            for (int m = 0; m < 2; m++) {
                int off = s * 2048 + (R0 + (m << 4) + lrow) * 32 + (kq << 3);
                ah[m] = *(const bf16x8*)&lds[off];
                al[m] = *(const bf16x8*)&lds[4096 + off];
            }
#pragma unroll
            for (int n = 0; n < 2; n++) {
                int off = s * 2048 + (C0 + (n << 4) + lrow) * 32 + (kq << 3);
                bh[n] = *(const bf16x8*)&lds[8192 + off];
                bl[n] = *(const bf16x8*)&lds[12288 + off];
            }
#pragma unroll
            for (int m = 0; m < 2; m++)
#pragma unroll
                for (int n = 0; n < 2; n++) {
                    acc[m][n] = __builtin_amdgcn_mfma_f32_16x16x32_bf16(ah[m], bh[n], acc[m][n], 0, 0, 0);
                    acc[m][n] = __builtin_amdgcn_mfma_f32_16x16x32_bf16(ah[m], bl[n], acc[m][n], 0, 0, 0);
                    acc[m][n] = __builtin_amdgcn_mfma_f32_16x16x32_bf16(al[m], bh[n], acc[m][n], 0, 0, 0);
                }
        }
        __syncthreads();
    }

#pragma unroll
    for (int m = 0; m < 2; m++)
#pragma unroll
        for (int n = 0; n < 2; n++) {
            int col = cbase + C0 + (n << 4) + lrow;
#pragma unroll
            for (int r = 0; r < 4; r++) {
                int row = rbase + R0 + (m << 4) + kq * 4 + r;
                if (row < M) Cbf[(size_t)row * N + col] = (u16)bf16_rne(acc[m][n][r]);
            }
        }

    // fused layer-2 scores: partial over this block's 64 cols -> atomicAdd
    {
        float* fl = (float*)lds;  // vs: fl[0..127], vd: fl[128..255]
        const int c01 = w & 1;
        float asv[2], adv[2];
#pragma unroll
        for (int n = 0; n < 2; n++) {
            int col = cbase + C0 + (n << 4) + lrow;
            asv[n] = a_s[col];
            adv[n] = a_d[col];
        }
#pragma unroll
        for (int m = 0; m < 2; m++)
#pragma unroll
            for (int r = 0; r < 4; r++) {
                float vs = asv[0] * acc[m][0][r] + asv[1] * acc[m][1][r];
                float vd = adv[0] * acc[m][0][r] + adv[1] * acc[m][1][r];
#pragma unroll
                for (int o = 1; o < 16; o <<= 1) {
                    vs += __shfl_xor(vs, o);
                    vd += __shfl_xor(vd, o);
                }
                if (lrow == 0) {
                    int lr = R0 + (m << 4) + kq * 4 + r;  // 0..63
                    fl[c01 * 64 + lr] = vs;
                    fl[128 + c01 * 64 + lr] = vd;
                }
            }
        __syncthreads();
        if (t < 64) {
            int row = rbase + t;
            if (row < M) {
                atomicAdd(&ssrc[row], fl[t] + fl[64 + t]);
                atomicAdd(&sdst[row], fl[128 + t] + fl[192 + t]);
            }
        }
    }
}

// ---------------- layer-1 edge softmax: per-edge alpha (fp32) ----------------
// 16-lane group per (d, h) task; 4 tasks/wave, 16 tasks/block.
// NOTE (round 6 lesson): fusing this into agg_mfma1 puts the alpha gather+exp
// on the producer wave's serial fill path -> +13us. Keep it separate.

__global__ __launch_bounds__(256) void softmax_edges1(
    const float* __restrict__ ssrc, const float* __restrict__ sdst,
    const int* __restrict__ start, const int* __restrict__ ssorted,
    float* __restrict__ alphab, int N, int ET) {
    int lane = threadIdx.x & 63;
    int p = lane & 15, g = lane >> 4;
    int task = (blockIdx.x * 4 + (threadIdx.x >> 6)) * 4 + g;
    if (task >= N * H1) return;
    int d = task >> 3, hh = task & 7;
    int s0 = start[d], ne = start[d + 1] - s0;
    float sd = sdst[d * H1 + hh];
    int src0 = 0; float v0 = -1e30f;
    if (p < ne) { src0 = ssorted[s0 + p]; v0 = lrelu(ssrc[src0 * H1 + hh] + sd); }
    float m = v0;
    for (int e = p + 16; e < ne; e += 16)
        m = fmaxf(m, lrelu(ssrc[ssorted[s0 + e] * H1 + hh] + sd));
    for (int o = 8; o; o >>= 1) m = fmaxf(m, __shfl_xor(m, o));
    float p0 = (p < ne) ? __expf(v0 - m) : 0.f;
    float s = p0;
    for (int e = p + 16; e < ne; e += 16)
        s += __expf(lrelu(ssrc[ssorted[s0 + e] * H1 + hh] + sd) - m);
    for (int o = 8; o; o >>= 1) s += __shfl_xor(s, o);
    float inv = 1.f / s;
    float* ab = alphab + (size_t)hh * ET;
    if (p < ne) ab[s0 + p] = p0 * inv;
    for (int e = p + 16; e < ne; e += 16)
        ab[s0 + e] = __expf(lrelu(ssrc[ssorted[s0 + e] * H1 + hh] + sd) - m) * inv;
}

// ---------------- layer-1 aggregation via MFMA (segmented SpMM) ----------------
// Block = 16 consecutive dsts x 1 head; 4 waves; wave w owns interleaved
// channels ch = 32w + 2*cl + nn (nn in {0,1}) -> one dword gather per edge.
// A-tile in LDS: A32[row][k] = alpha_hi|alpha_lo<<16, built ONCE per chunk
// from the COALESCED alpha stream. CHUNK = 64 edges, double-buffered A/mOff
// -> one barrier per chunk. PRODUCER ROTATION (r12): chunk i is filled by
// wave i&3, so fill cost amortizes 4x instead of riding wave 0's critical
// path every chunk (r10 counters: no pipe saturated -> critical-path bound).
// No atomics: block owns its 16 rows.

__global__ __launch_bounds__(256) void agg_mfma1(
    const u16* __restrict__ hbf,               // [N][H1*C1] bf16
    const float* __restrict__ alphab,          // [H1][ET] fp32
    const unsigned char* __restrict__ rowloc,  // [ET] = dst & 15
    const int* __restrict__ start,
    const int* __restrict__ ssorted,
    const float* __restrict__ bias,            // [H1*C1]
    u16* __restrict__ outHi, u16* __restrict__ outLo,
    int N, int ET) {
    __shared__ unsigned A32[2][16 * 68];  // 2 x 4.25 KB, padded stride
    __shared__ int mOff[2][64];           // src row byte offsets (src * 2048)

    const int hh = blockIdx.x & 7;  // head -> XCD locality
    const int g = blockIdx.x >> 3;
    const int t = threadIdx.x;
    const int w = t >> 6;
    const int lane = t & 63;
    const int cl = lane & 15, q = lane >> 4;

    const int d0 = g * 16;
    const int e0 = start[d0], e1 = start[min(d0 + 16, N)];
    const float* ab = alphab + (size_t)hh * ET;

    const int lanebyte = hh * 256 + w * 64 + 4 * cl;
    const char* hbase = (const char*)hbf;  // uniform base -> saddr loads

    const int nk = (e1 - e0 + 63) >> 6;

    auto fill = [&](int b, int kb) {
        unsigned* Az = &A32[b][(lane >> 2) * 68 + (lane & 3) * 16];
        uint4 z = {0u, 0u, 0u, 0u};
        *(uint4*)(Az) = z;
        *(uint4*)(Az + 4) = z;
        *(uint4*)(Az + 8) = z;
        *(uint4*)(Az + 12) = z;
        int pos = kb + lane;
        bool valid = pos < e1;
        int ps = valid ? pos : e0;
        float af = valid ? ab[ps] : 0.f;
        unsigned ahiu = bf16_rne(af);
        unsigned alou = bf16_rne(af - __uint_as_float(ahiu << 16));
        int rr = rowloc[ps];
        mOff[b][lane] = ssorted[ps] << 11;
        asm volatile("s_waitcnt lgkmcnt(0)" ::: "memory");
        A32[b][rr * 68 + lane] = ahiu | (alou << 16);
    };

    f32x4 acc0 = {}, acc1 = {};

    if (w == 0 && nk > 0) fill(0, e0);  // chunk 0 filled by wave 0 (= 0 & 3)

    for (int i = 0; i < nk; ++i) {
        __syncthreads();
        const int b = i & 1;
        // producer rotation: chunk i+1 filled by wave (i+1)&3
        if (w == ((i + 1) & 3) && i + 1 < nk) fill(b ^ 1, e0 + (i + 1) * 64);

        const int mb = q * 8;
        int4 o0 = *(const int4*)&mOff[b][mb];
        int4 o1 = *(const int4*)&mOff[b][mb + 4];
        int4 o2 = *(const int4*)&mOff[b][32 + mb];
        int4 o3 = *(const int4*)&mOff[b][32 + mb + 4];
        int oo[16] = {o0.x, o0.y, o0.z, o0.w, o1.x, o1.y, o1.z, o1.w,
                      o2.x, o2.y, o2.z, o2.w, o3.x, o3.y, o3.z, o3.w};

        unsigned gld[16];
#pragma unroll
        for (int j = 0; j < 16; j++)
            gld[j] = *(const unsigned*)(hbase + (unsigned)(oo[j] + lanebyte));

        const unsigned* Ar = &A32[b][cl * 68 + mb];
        uint4 a0 = *(const uint4*)(Ar);
        uint4 a1 = *(const uint4*)(Ar + 4);
        uint4 a2 = *(const uint4*)(Ar + 32);
        uint4 a3 = *(const uint4*)(Ar + 36);
        unsigned aw[16] = {a0.x, a0.y, a0.z, a0.w, a1.x, a1.y, a1.z, a1.w,
                           a2.x, a2.y, a2.z, a2.w, a3.x, a3.y, a3.z, a3.w};

        union { unsigned u[4]; bf16x8 v; } ahi0, alo0, ahi1, alo1, b00, b10, b01, b11;
#pragma unroll
        for (int r = 0; r < 4; r++) {
            ahi0.u[r] = __builtin_amdgcn_perm(aw[2 * r + 1], aw[2 * r], 0x05040100u);
            alo0.u[r] = __builtin_amdgcn_perm(aw[2 * r + 1], aw[2 * r], 0x07060302u);
            ahi1.u[r] = __builtin_amdgcn_perm(aw[8 + 2 * r + 1], aw[8 + 2 * r], 0x05040100u);
            alo1.u[r] = __builtin_amdgcn_perm(aw[8 + 2 * r + 1], aw[8 + 2 * r], 0x07060302u);
            b00.u[r] = __builtin_amdgcn_perm(gld[2 * r + 1], gld[2 * r], 0x05040100u);
            b10.u[r] = __builtin_amdgcn_perm(gld[2 * r + 1], gld[2 * r], 0x07060302u);
            b01.u[r] = __builtin_amdgcn_perm(gld[8 + 2 * r + 1], gld[8 + 2 * r], 0x05040100u);
            b11.u[r] = __builtin_amdgcn_perm(gld[8 + 2 * r + 1], gld[8 + 2 * r], 0x07060302u);
        }

        acc0 = __builtin_amdgcn_mfma_f32_16x16x32_bf16(ahi0.v, b00.v, acc0, 0, 0, 0);
        acc0 = __builtin_amdgcn_mfma_f32_16x16x32_bf16(alo0.v, b00.v, acc0, 0, 0, 0);
        acc1 = __builtin_amdgcn_mfma_f32_16x16x32_bf16(ahi0.v, b10.v, acc1, 0, 0, 0);
        acc1 = __builtin_amdgcn_mfma_f32_16x16x32_bf16(alo0.v, b10.v, acc1, 0, 0, 0);
        acc0 = __builtin_amdgcn_mfma_f32_16x16x32_bf16(ahi1.v, b01.v, acc0, 0, 0, 0);
        acc0 = __builtin_amdgcn_mfma_f32_16x16x32_bf16(alo1.v, b01.v, acc0, 0, 0, 0);
        acc1 = __builtin_amdgcn_mfma_f32_16x16x32_bf16(ahi1.v, b11.v, acc1, 0, 0, 0);
        acc1 = __builtin_amdgcn_mfma_f32_16x16x32_bf16(alo1.v, b11.v, acc1, 0, 0, 0);
    }

    {
        int chbase = w * 32 + 2 * cl;
        float bv0 = bias[hh * C1 + chbase];
        float bv1 = bias[hh * C1 + chbase + 1];
#pragma unroll
        for (int r = 0; r < 4; r++) {
            int d = d0 + q * 4 + r;
            if (d >= N) continue;
            float v0 = acc0[r] + bv0;
            float v1 = acc1[r] + bv1;
            v0 = v0 > 0.f ? v0 : expm1f(v0);
            v1 = v1 > 0.f ? v1 : expm1f(v1);
            unsigned hi, lo;
            split2(v0, v1, hi, lo);
            size_t idx = (size_t)d * HC1 + hh * C1 + chbase;  // even
            ((unsigned*)outHi)[idx >> 1] = hi;
            ((unsigned*)outLo)[idx >> 1] = lo;
        }
    }
}

// ---------------- aggregation: one wave per (dst, head) (layer 2) ----------------

template<int H, bool SPLITOUT>
__global__ __launch_bounds__(256) void agg_bf(const unsigned* __restrict__ hbf,
                                              const float* __restrict__ ssrc,
                                              const float* __restrict__ sdst,
                                              const int* __restrict__ start,
                                              const int* __restrict__ ssorted,
                                              const float* __restrict__ bias,
                                              float* __restrict__ out,
                                              unsigned* __restrict__ outHi,
                                              unsigned* __restrict__ outLo, int N) {
    int hh, grp;
    if (H == 8) { hh = blockIdx.x & 7; grp = blockIdx.x >> 3; }
    else        { hh = 0;              grp = blockIdx.x; }
    int wid = threadIdx.x >> 6, lane = threadIdx.x & 63;
    int d = grp * 4 + wid;
    if (d >= N) return;
    const int g = lane >> 4, p = lane & 15;
    int s0 = start[d];
    int ne = start[d + 1] - s0;
    float sd = sdst[d * H + hh];

    const unsigned* hlane = hbf + hh * 64 + p * 4;
    const int rowstride = H * 64;

    int src0 = 0; float v0 = -1e30f;
    if (lane < ne) { src0 = ssorted[s0 + lane]; v0 = lrelu(ssrc[src0 * H + hh] + sd); }
    float m = v0;
    for (int e = lane + 64; e < ne; e += 64)
        m = fmaxf(m, lrelu(ssrc[ssorted[s0 + e] * H + hh] + sd));
    for (int o = 32; o; o >>= 1) m = fmaxf(m, __shfl_xor(m, o));

    float p0 = (lane < ne) ? __expf(v0 - m) : 0.f;
    float ssum = p0;
    for (int e = lane + 64; e < ne; e += 64)
        ssum += __expf(lrelu(ssrc[ssorted[s0 + e] * H + hh] + sd) - m);
    for (int o = 32; o; o >>= 1) ssum += __shfl_xor(ssum, o);
    float inv = 1.f / ssum;

    float acc[8] = {};
    for (int base = 0; base < ne; base += 64) {
        int srcr; float al;
        if (base == 0) { srcr = src0; al = p0 * inv; }
        else {
            srcr = 0; al = 0.f;
            int e = base + lane;
            if (e < ne) {
                srcr = ssorted[s0 + e];
                al = __expf(lrelu(ssrc[srcr * H + hh] + sd) - m) * inv;
            }
        }
        int cnt = min(64, ne - base);
        for (int e2 = 0; e2 < cnt; e2 += 4) {
            float a = __shfl(al, e2 + g);
            int sr = __shfl(srcr, e2 + g);
            uint4 u = *(const uint4*)(hlane + (size_t)sr * rowstride);
            acc[0] += a * __uint_as_float(u.x << 16);
            acc[1] += a * __uint_as_float(u.x & 0xffff0000u);
            acc[2] += a * __uint_as_float(u.y << 16);
            acc[3] += a * __uint_as_float(u.y & 0xffff0000u);
            acc[4] += a * __uint_as_float(u.z << 16);
            acc[5] += a * __uint_as_float(u.z & 0xffff0000u);
            acc[6] += a * __uint_as_float(u.w << 16);
            acc[7] += a * __uint_as_float(u.w & 0xffff0000u);
        }
    }

#pragma unroll
    for (int i = 0; i < 8; i++) {
        acc[i] += __shfl_xor(acc[i], 16);
        acc[i] += __shfl_xor(acc[i], 32);
    }

    float r0 = g == 0 ? acc[0] : g == 1 ? acc[2] : g == 2 ? acc[4] : acc[6];
    float r1 = g == 0 ? acc[1] : g == 1 ? acc[3] : g == 2 ? acc[5] : acc[7];
    int j = 4 * p + g;
    float2 bv = ((const float2*)bias)[hh * 64 + j];
    r0 += bv.x; r1 += bv.y;
    size_t idx = (size_t)d * (H * 64) + hh * 64 + j;
    if (SPLITOUT) {
        r0 = r0 > 0.f ? r0 : expm1f(r0);
        r1 = r1 > 0.f ? r1 : expm1f(r1);
        unsigned hi, lo;
        split2(r0, r1, hi, lo);
        outHi[idx] = hi;
        outLo[idx] = lo;
    } else {
        ((float2*)out)[idx] = make_float2(r0, r1);
    }
}

// ---------------- launch ----------------

extern "C" void kernel_launch(void* const* d_in, const int* in_sizes, int n_in,
                              void* d_out, int out_size, void* d_ws, size_t ws_size,
                              hipStream_t stream) {
    const float* x      = (const float*)d_in[0];
    const int*   ei     = (const int*)d_in[1];
    const float* W1     = (const float*)d_in[2];
    const float* a_src1 = (const float*)d_in[3];
    const float* a_dst1 = (const float*)d_in[4];
    const float* b1     = (const float*)d_in[5];
    const float* W2     = (const float*)d_in[6];
    const float* a_src2 = (const float*)d_in[7];
    const float* a_dst2 = (const float*)d_in[8];
    const float* b2     = (const float*)d_in[9];
    float* out = (float*)d_out;

    int E = in_sizes[1] / 2;
    int N = in_sizes[0] / F_IN;
    int ET = E + N;
    const int* esrc = ei;
    const int* edst = ei + E;

    char* ws = (char*)d_ws;
    size_t off = 0;
    auto alloc = [&](size_t bytes) -> char* {
        char* p = ws + off;
        off = (off + bytes + 255) & ~(size_t)255;
        return p;
    };
    u16* x_hi    = (u16*)alloc((size_t)N * F_IN * 2);
    u16* x_lo    = (u16*)alloc((size_t)N * F_IN * 2);
    u16* W1t_hi  = (u16*)alloc((size_t)F_IN * HC1 * 2);
    u16* W1t_lo  = (u16*)alloc((size_t)F_IN * HC1 * 2);
    u16* W2t_hi  = (u16*)alloc((size_t)HC1 * C2 * 2);
    u16* W2t_lo  = (u16*)alloc((size_t)HC1 * C2 * 2);
    u16* h1_bf   = (u16*)alloc((size_t)N * HC1 * 2);
    u16* h1a_hi  = (u16*)alloc((size_t)N * HC1 * 2);
    u16* h1a_lo  = (u16*)alloc((size_t)N * HC1 * 2);
    u16* h2_bf   = (u16*)alloc((size_t)N * C2 * 2);
    float* ss1   = (float*)alloc((size_t)N * H1 * 4);
    float* sd1   = (float*)alloc((size_t)N * H1 * 4);
    float* ss2   = (float*)alloc((size_t)N * 4);
    float* sd2   = (float*)alloc((size_t)N * 4);
    int* deg     = (int*)alloc((size_t)N * 4);
    int* startp  = (int*)alloc((size_t)(N + 1) * 4);
    int* cursor  = (int*)alloc((size_t)N * 4);
    int* ssorted = (int*)alloc((size_t)ET * 4);
    unsigned char* rowloc = (unsigned char*)alloc((size_t)ET);
    // alpha1 [H1][ET] fp32 (5.44 MB) aliases x_hi/x_lo (10.24 MB):
    // x_* are dead after gemm_mfma; softmax_edges1 runs strictly after it.
    float* alpha1 = (float*)x_hi;

    // x split + deg init (deg=1 self-loop), then edge sort by destination
    split_mat_deg<<<(N * F_IN + 255) / 256, 256, 0, stream>>>(x, x_hi, x_lo, N * F_IN, deg, N);
    hist_kernel<<<(E + 255) / 256, 256, 0, stream>>>(edst, deg, E);
    scan_kernel<<<1, 1024, 0, stream>>>(deg, startp, cursor, N);
    scatter_kernel<<<(E + N + 255) / 256, 256, 0, stream>>>(esrc, edst, cursor, ssorted, rowloc, E, N);

    // weight splits (merged) + zero ss2/sd2 for the fused layer-2 scores
    split_transpose2<<<(F_IN * HC1 + HC1 * C2 + 255) / 256, 256, 0, stream>>>(
        W1, W1t_hi, W1t_lo, F_IN, HC1, W2, W2t_hi, W2t_lo, HC1, C2, ss2, sd2, N);

    // layer 1 (scores fused into GEMM epilogue)
    gemm_mfma<<<dim3(HC1 / 128, (N + 127) / 128), 256, 0, stream>>>(
        x_hi, x_lo, W1t_hi, W1t_lo, h1_bf, N, HC1, F_IN, a_src1, a_dst1, ss1, sd1);
    softmax_edges1<<<(N * H1 + 15) / 16, 256, 0, stream>>>(
        ss1, sd1, startp, ssorted, alpha1, N, ET);
    agg_mfma1<<<((N + 15) / 16) * H1, 256, 0, stream>>>(
        h1_bf, alpha1, rowloc, startp, ssorted, b1, h1a_hi, h1a_lo, N, ET);

    // layer 2 (64x64 tiles, BK=64; scores2 fused into epilogue via atomicAdd)
    gemm_mfma64<<<dim3(C2 / 64, (N + 63) / 64), 256, 0, stream>>>(
        h1a_hi, h1a_lo, W2t_hi, W2t_lo, h2_bf, N, C2, HC1, a_src2, a_dst2, ss2, sd2);
    agg_bf<1, false><<<(N + 3) / 4, 256, 0, stream>>>(
        (const unsigned*)h2_bf, ss2, sd2, startp, ssorted, b2,
        out, nullptr, nullptr, N);
}

// Round 13
// 225.913 us; speedup vs baseline: 1.0361x; 1.0361x over previous
//
#include <hip/hip_runtime.h>
#include <math.h>

#define F_IN 256
#define H1 8
#define C1 128
#define HC1 1024
#define C2 128
#define SLOPE 0.2f

typedef unsigned short u16;
typedef __attribute__((ext_vector_type(8))) short bf16x8;
typedef __attribute__((ext_vector_type(4))) float f32x4;

// ---------------- helpers ----------------

__device__ __forceinline__ float lrelu(float v) { return v > 0.f ? v : SLOPE * v; }

__device__ __forceinline__ unsigned bf16_rne(float x) {
    unsigned u = __float_as_uint(x);
    u += 0x7fffu + ((u >> 16) & 1u);
    return u >> 16;
}

// split a,b into packed-bf16 hi pair and lo pair (lo = exact residual, rounded)
__device__ __forceinline__ void split2(float a, float b, unsigned& hi, unsigned& lo) {
    unsigned ha = bf16_rne(a), hb = bf16_rne(b);
    float fa = __uint_as_float(ha << 16), fb = __uint_as_float(hb << 16);
    hi = ha | (hb << 16);
    lo = bf16_rne(a - fa) | (bf16_rne(b - fb) << 16);
}

__device__ __forceinline__ void gload16(const u16* g, u16* l) {
    __builtin_amdgcn_global_load_lds(
        (const __attribute__((address_space(1))) unsigned*)g,
        (__attribute__((address_space(3))) unsigned*)l, 16, 0, 0);
}

// ---------------- edge sorting (counting sort by dst) ----------------

__global__ void hist_kernel(const int* __restrict__ dst, int* __restrict__ deg, int E) {
    int i = blockIdx.x * blockDim.x + threadIdx.x;
    if (i < E) atomicAdd(&deg[dst[i]], 1);
}

// wave-shuffle two-level scan: 3 barriers/chunk (was 20)
__global__ void scan_kernel(const int* __restrict__ deg, int* __restrict__ start,
                            int* __restrict__ cursor, int n) {
    __shared__ int wsum[16];
    __shared__ int wpre[16];
    __shared__ int ctot;
    const int tid = threadIdx.x;
    const int lane = tid & 63, wv = tid >> 6;
    int carry = 0;
    for (int base = 0; base < n; base += 1024) {
        int i = base + tid;
        int v = (i < n) ? deg[i] : 0;
        int x = v;  // inclusive wave scan
#pragma unroll
        for (int o = 1; o < 64; o <<= 1) {
            int y = __shfl_up(x, o);
            if (lane >= o) x += y;
        }
        if (lane == 63) wsum[wv] = x;
        __syncthreads();
        if (tid < 16) {
            int s = wsum[tid];
            int xx = s;
#pragma unroll
            for (int o = 1; o < 16; o <<= 1) {
                int y = __shfl_up(xx, o);
                if (tid >= o) xx += y;
            }
            wpre[tid] = xx - s;        // exclusive prefix of wave sums
            if (tid == 15) ctot = xx;  // chunk total
        }
        __syncthreads();
        int excl = carry + wpre[wv] + (x - v);
        if (i < n) { start[i] = excl; cursor[i] = excl; }
        carry += ctot;
        __syncthreads();  // protect wsum/wpre/ctot for next chunk
    }
    if (tid == 0) start[n] = carry;
}

__global__ void scatter_kernel(const int* __restrict__ src, const int* __restrict__ dst,
                               int* __restrict__ cursor, int* __restrict__ ssorted,
                               unsigned char* __restrict__ rowloc,
                               int E, int N) {
    int i = blockIdx.x * blockDim.x + threadIdx.x;
    if (i < E) {
        int d = dst[i];
        int pos = atomicAdd(&cursor[d], 1);
        ssorted[pos] = src[i];
        rowloc[pos] = (unsigned char)(d & 15);
    } else if (i < E + N) {
        int d = i - E;
        int pos = atomicAdd(&cursor[d], 1);
        ssorted[pos] = d;
        rowloc[pos] = (unsigned char)(d & 15);
    }
}

// ---------------- all elementwise prep in ONE kernel ----------------
// x hi/lo split + deg=1 init + ss2/sd2 zero + W1/W2 transposed splits.
// All writes disjoint & order-free; hist (consumer of deg) runs after.

__global__ void split_all(const float* __restrict__ x, u16* __restrict__ xhi,
                          u16* __restrict__ xlo, int nx,
                          const float* __restrict__ W1, u16* __restrict__ w1hi,
                          u16* __restrict__ w1lo, int R1, int Cc1,
                          const float* __restrict__ W2, u16* __restrict__ w2hi,
                          u16* __restrict__ w2lo, int R2, int Cc2,
                          int* __restrict__ deg, float* __restrict__ z1,
                          float* __restrict__ z2, int N) {
    int i = blockIdx.x * blockDim.x + threadIdx.x;
    if (i < N) { deg[i] = 1; z1[i] = 0.f; z2[i] = 0.f; }
    if (i < nx) {
        float v = x[i];
        unsigned h = bf16_rne(v);
        xhi[i] = (u16)h;
        xlo[i] = (u16)bf16_rne(v - __uint_as_float(h << 16));
    }
    int n1 = R1 * Cc1;
    if (i < n1) {
        int r = i / Cc1, c = i % Cc1;
        float v = W1[i];
        unsigned h = bf16_rne(v);
        w1hi[(size_t)c * R1 + r] = (u16)h;
        w1lo[(size_t)c * R1 + r] = (u16)bf16_rne(v - __uint_as_float(h << 16));
    } else if (i - n1 < R2 * Cc2) {
        int j = i - n1;
        int r = j / Cc2, c = j % Cc2;
        float v = W2[j];
        unsigned h = bf16_rne(v);
        w2hi[(size_t)c * R2 + r] = (u16)h;
        w2lo[(size_t)c * R2 + r] = (u16)bf16_rne(v - __uint_as_float(h << 16));
    }
}

// ---------------- split-bf16 MFMA GEMM, 128x128 tile, fused scores ----------
// C[M,N](bf16) = (Ahi+Alo)[M,K] @ (Bhi+Blo)^T[N,K], fp32 accumulate.
// Layer-1 only: col tile 128 = exactly one head -> the block computes that
// head's s_src/s_dst for its 128 rows in the epilogue (fp32 acc, lrow
// butterfly + 2KB LDS cross-wave combine). Replaces the scores1_bf kernel.

__global__ __launch_bounds__(256) void gemm_mfma(const u16* __restrict__ Ahi,
                                                 const u16* __restrict__ Alo,
                                                 const u16* __restrict__ Bhi,
                                                 const u16* __restrict__ Blo,
                                                 u16* __restrict__ Cbf,
                                                 int M, int N, int K,
                                                 const float* __restrict__ a_s,
                                                 const float* __restrict__ a_d,
                                                 float* __restrict__ ssrc,
                                                 float* __restrict__ sdst) {
    __shared__ u16 lds[16384];  // 4 tiles x [128][32] bf16 = 32 KB
    const int t = threadIdx.x;
    const int rbase = blockIdx.y * 128;
    const int cbase = blockIdx.x * 128;

    const int lane = t & 63;
    const int R0 = (t >> 7) << 6;
    const int C0 = ((t >> 6) & 1) << 6;
    const int lrow = lane & 15;
    const int kq = lane >> 4;

    f32x4 acc[4][4] = {};

    for (int k0 = 0; k0 < K; k0 += 32) {
#pragma unroll
        for (int i = 0; i < 2; i++) {
            int c = t + (i << 8);
            int row = c >> 2;
            int kc = (c & 3) << 3;
            int ar = min(rbase + row, M - 1);
            int br = cbase + row;
            gload16(Ahi + (size_t)ar * K + k0 + kc, &lds[c * 8]);
            gload16(Alo + (size_t)ar * K + k0 + kc, &lds[4096 + c * 8]);
            gload16(Bhi + (size_t)br * K + k0 + kc, &lds[8192 + c * 8]);
            gload16(Blo + (size_t)br * K + k0 + kc, &lds[12288 + c * 8]);
        }
        __syncthreads();

        bf16x8 ah[4], al[4], bh[4], bl[4];
#pragma unroll
        for (int m = 0; m < 4; m++) {
            int off = (R0 + (m << 4) + lrow) * 32 + (kq << 3);
            ah[m] = *(const bf16x8*)&lds[off];
            al[m] = *(const bf16x8*)&lds[4096 + off];
        }
#pragma unroll
        for (int n = 0; n < 4; n++) {
            int off = (C0 + (n << 4) + lrow) * 32 + (kq << 3);
            bh[n] = *(const bf16x8*)&lds[8192 + off];
            bl[n] = *(const bf16x8*)&lds[12288 + off];
        }
#pragma unroll
        for (int m = 0; m < 4; m++)
#pragma unroll
            for (int n = 0; n < 4; n++) {
                acc[m][n] = __builtin_amdgcn_mfma_f32_16x16x32_bf16(ah[m], bh[n], acc[m][n], 0, 0, 0);
                acc[m][n] = __builtin_amdgcn_mfma_f32_16x16x32_bf16(ah[m], bl[n], acc[m][n], 0, 0, 0);
                acc[m][n] = __builtin_amdgcn_mfma_f32_16x16x32_bf16(al[m], bh[n], acc[m][n], 0, 0, 0);
            }
        __syncthreads();
    }

    // C store
#pragma unroll
    for (int m = 0; m < 4; m++)
#pragma unroll
        for (int n = 0; n < 4; n++) {
            int col = cbase + C0 + (n << 4) + lrow;
#pragma unroll
            for (int r = 0; r < 4; r++) {
                int row = rbase + R0 + (m << 4) + kq * 4 + r;
                if (row < M) Cbf[(size_t)row * N + col] = (u16)bf16_rne(acc[m][n][r]);
            }
        }

    // fused scores for head = blockIdx.x (staging LDS is free after the loop)
    {
        float* fl = (float*)lds;     // sS = fl[0..255], sD = fl[256..511]
        const int head = blockIdx.x;
        const int c01 = (t >> 6) & 1;
        float asv[4], adv[4];
#pragma unroll
        for (int n = 0; n < 4; n++) {
            int col = head * 128 + C0 + (n << 4) + lrow;
            asv[n] = a_s[col];
            adv[n] = a_d[col];
        }
#pragma unroll
        for (int m = 0; m < 4; m++)
#pragma unroll
            for (int r = 0; r < 4; r++) {
                float vs = 0.f, vd = 0.f;
#pragma unroll
                for (int n = 0; n < 4; n++) {
                    float h = acc[m][n][r];
                    vs += asv[n] * h;
                    vd += adv[n] * h;
                }
#pragma unroll
                for (int o = 1; o < 16; o <<= 1) {  // reduce over lrow (16 lanes)
                    vs += __shfl_xor(vs, o);
                    vd += __shfl_xor(vd, o);
                }
                if (lrow == 0) {
                    int lr = R0 + (m << 4) + kq * 4 + r;
                    fl[c01 * 128 + lr] = vs;
                    fl[256 + c01 * 128 + lr] = vd;
                }
            }
        __syncthreads();
        if (t < 128) {
            int row = rbase + t;
            if (row < M) {
                ssrc[row * H1 + head] = fl[t] + fl[128 + t];
                sdst[row * H1 + head] = fl[256 + t] + fl[384 + t];
            }
        }
    }
}

// ---------------- split-bf16 MFMA GEMM, 64x64 tile, BK=64, fused scores2 ----
// Two [64][32] sub-tiles per operand per iteration -> 16 K-iterations,
// 24 MFMAs per barrier pair.  [verified passing, rounds 6-9]
// Layer-2 scores fused (r8 pattern): per-row partial over this block's 64
// cols from fp32 acc, lrow butterfly + LDS combine, then atomicAdd into
// ss2/sd2 (2 commutative adds onto exact 0 -> deterministic).

__global__ __launch_bounds__(256) void gemm_mfma64(const u16* __restrict__ Ahi,
                                                   const u16* __restrict__ Alo,
                                                   const u16* __restrict__ Bhi,
                                                   const u16* __restrict__ Blo,
                                                   u16* __restrict__ Cbf,
                                                   int M, int N, int K,
                                                   const float* __restrict__ a_s,
                                                   const float* __restrict__ a_d,
                                                   float* __restrict__ ssrc,
                                                   float* __restrict__ sdst) {
    __shared__ u16 lds[16384];  // 4 operands x [2 ksub][64][32] bf16 = 32 KB
    const int t = threadIdx.x;
    const int rbase = blockIdx.y * 64;
    const int cbase = blockIdx.x * 64;

    const int lane = t & 63;
    const int w = t >> 6;
    const int R0 = (w >> 1) << 5;   // 0 / 32
    const int C0 = (w & 1) << 5;    // 0 / 32
    const int lrow = lane & 15;
    const int kq = lane >> 4;

    f32x4 acc[2][2] = {};

    for (int k0 = 0; k0 < K; k0 += 64) {
        {
            int row = (w << 4) + (lane >> 2);
            int kcc = (lane & 3) << 3;
            int ar = min(rbase + row, M - 1);
            int br = cbase + row;
            const size_t ga = (size_t)ar * K + k0 + kcc;
            const size_t gb = (size_t)br * K + k0 + kcc;
            const int ldo = row * 32 + kcc;
#pragma unroll
            for (int s2 = 0; s2 < 2; s2++) {
                gload16(Ahi + ga + s2 * 32, &lds[s2 * 2048 + ldo]);
                gload16(Alo + ga + s2 * 32, &lds[4096 + s2 * 2048 + ldo]);
                gload16(Bhi + gb + s2 * 32, &lds[8192 + s2 * 2048 + ldo]);
                gload16(Blo + gb + s2 * 32, &lds[12288 + s2 * 2048 + ldo]);
            }
        }
        __syncthreads();

#pragma unroll
        for (int s = 0; s < 2; s++) {
            bf16x8 ah[2], al[2], bh[2], bl[2];
#pragma unroll
            for (int m = 0; m < 2; m++) {
                int off = s * 2048 + (R0 + (m << 4) + lrow) * 32 + (kq << 3);
                ah[m] = *(const bf16x8*)&lds[off];
                al[m] = *(const bf16x8*)&lds[4096 + off];
            }
#pragma unroll
            for (int n = 0; n < 2; n++) {
                int off = s * 2048 + (C0 + (n << 4) + lrow) * 32 + (kq << 3);
                bh[n] = *(const bf16x8*)&lds[8192 + off];
                bl[n] = *(const bf16x8*)&lds[12288 + off];
            }
#pragma unroll
            for (int m = 0; m < 2; m++)
#pragma unroll
                for (int n = 0; n < 2; n++) {
                    acc[m][n] = __builtin_amdgcn_mfma_f32_16x16x32_bf16(ah[m], bh[n], acc[m][n], 0, 0, 0);
                    acc[m][n] = __builtin_amdgcn_mfma_f32_16x16x32_bf16(ah[m], bl[n], acc[m][n], 0, 0, 0);
                    acc[m][n] = __builtin_amdgcn_mfma_f32_16x16x32_bf16(al[m], bh[n], acc[m][n], 0, 0, 0);
                }
        }
        __syncthreads();
    }

#pragma unroll
    for (int m = 0; m < 2; m++)
#pragma unroll
        for (int n = 0; n < 2; n++) {
            int col = cbase + C0 + (n << 4) + lrow;
#pragma unroll
            for (int r = 0; r < 4; r++) {
                int row = rbase + R0 + (m << 4) + kq * 4 + r;
                if (row < M) Cbf[(size_t)row * N + col] = (u16)bf16_rne(acc[m][n][r]);
            }
        }

    // fused layer-2 scores: partial over this block's 64 cols -> atomicAdd
    {
        float* fl = (float*)lds;  // vs: fl[0..127], vd: fl[128..255]
        const int c01 = w & 1;
        float asv[2], adv[2];
#pragma unroll
        for (int n = 0; n < 2; n++) {
            int col = cbase + C0 + (n << 4) + lrow;
            asv[n] = a_s[col];
            adv[n] = a_d[col];
        }
#pragma unroll
        for (int m = 0; m < 2; m++)
#pragma unroll
            for (int r = 0; r < 4; r++) {
                float vs = asv[0] * acc[m][0][r] + asv[1] * acc[m][1][r];
                float vd = adv[0] * acc[m][0][r] + adv[1] * acc[m][1][r];
#pragma unroll
                for (int o = 1; o < 16; o <<= 1) {
                    vs += __shfl_xor(vs, o);
                    vd += __shfl_xor(vd, o);
                }
                if (lrow == 0) {
                    int lr = R0 + (m << 4) + kq * 4 + r;  // 0..63
                    fl[c01 * 64 + lr] = vs;
                    fl[128 + c01 * 64 + lr] = vd;
                }
            }
        __syncthreads();
        if (t < 64) {
            int row = rbase + t;
            if (row < M) {
                atomicAdd(&ssrc[row], fl[t] + fl[64 + t]);
                atomicAdd(&sdst[row], fl[128 + t] + fl[192 + t]);
            }
        }
    }
}

// ---------------- layer-1 edge softmax: per-edge alpha (fp32) ----------------
// 16-lane group per (d, h) task; 4 tasks/wave, 16 tasks/block.
// NOTE (round 6 lesson): fusing this into agg_mfma1 puts the alpha gather+exp
// on the producer wave's serial fill path -> +13us. Keep it separate.

__global__ __launch_bounds__(256) void softmax_edges1(
    const float* __restrict__ ssrc, const float* __restrict__ sdst,
    const int* __restrict__ start, const int* __restrict__ ssorted,
    float* __restrict__ alphab, int N, int ET) {
    int lane = threadIdx.x & 63;
    int p = lane & 15, g = lane >> 4;
    int task = (blockIdx.x * 4 + (threadIdx.x >> 6)) * 4 + g;
    if (task >= N * H1) return;
    int d = task >> 3, hh = task & 7;
    int s0 = start[d], ne = start[d + 1] - s0;
    float sd = sdst[d * H1 + hh];
    int src0 = 0; float v0 = -1e30f;
    if (p < ne) { src0 = ssorted[s0 + p]; v0 = lrelu(ssrc[src0 * H1 + hh] + sd); }
    float m = v0;
    for (int e = p + 16; e < ne; e += 16)
        m = fmaxf(m, lrelu(ssrc[ssorted[s0 + e] * H1 + hh] + sd));
    for (int o = 8; o; o >>= 1) m = fmaxf(m, __shfl_xor(m, o));
    float p0 = (p < ne) ? __expf(v0 - m) : 0.f;
    float s = p0;
    for (int e = p + 16; e < ne; e += 16)
        s += __expf(lrelu(ssrc[ssorted[s0 + e] * H1 + hh] + sd) - m);
    for (int o = 8; o; o >>= 1) s += __shfl_xor(s, o);
    float inv = 1.f / s;
    float* ab = alphab + (size_t)hh * ET;
    if (p < ne) ab[s0 + p] = p0 * inv;
    for (int e = p + 16; e < ne; e += 16)
        ab[s0 + e] = __expf(lrelu(ssrc[ssorted[s0 + e] * H1 + hh] + sd) - m) * inv;
}

// ---------------- layer-1 aggregation via MFMA (segmented SpMM) ----------------
// Block = 16 consecutive dsts x 1 head; 4 waves; wave w owns interleaved
// channels ch = 32w + 2*cl + nn (nn in {0,1}) -> one dword gather per edge.
// A-tile in LDS: A32[row][k] = alpha_hi|alpha_lo<<16, built ONCE per chunk
// by wave 0 (zero + scatter) from the COALESCED alpha stream.
// CHUNK = 64 edges, double-buffered A/mOff -> one barrier per chunk.
// No atomics: block owns its 16 rows.  [r11 version VERBATIM — r10 role-split
// and r12 producer-rotation both regressed; this form is the local optimum]

__global__ __launch_bounds__(256) void agg_mfma1(
    const u16* __restrict__ hbf,               // [N][H1*C1] bf16
    const float* __restrict__ alphab,          // [H1][ET] fp32
    const unsigned char* __restrict__ rowloc,  // [ET] = dst & 15
    const int* __restrict__ start,
    const int* __restrict__ ssorted,
    const float* __restrict__ bias,            // [H1*C1]
    u16* __restrict__ outHi, u16* __restrict__ outLo,
    int N, int ET) {
    __shared__ unsigned A32[2][16 * 68];  // 2 x 4.25 KB, padded stride
    __shared__ int mOff[2][64];           // src row byte offsets (src * 2048)

    const int hh = blockIdx.x & 7;  // head -> XCD locality
    const int g = blockIdx.x >> 3;
    const int t = threadIdx.x;
    const int w = t >> 6;
    const int lane = t & 63;
    const int cl = lane & 15, q = lane >> 4;

    const int d0 = g * 16;
    const int e0 = start[d0], e1 = start[min(d0 + 16, N)];
    const float* ab = alphab + (size_t)hh * ET;

    const int lanebyte = hh * 256 + w * 64 + 4 * cl;
    const char* hbase = (const char*)hbf;  // uniform base -> saddr loads

    const int nk = (e1 - e0 + 63) >> 6;

    auto fill = [&](int b, int kb) {
        unsigned* Az = &A32[b][(lane >> 2) * 68 + (lane & 3) * 16];
        uint4 z = {0u, 0u, 0u, 0u};
        *(uint4*)(Az) = z;
        *(uint4*)(Az + 4) = z;
        *(uint4*)(Az + 8) = z;
        *(uint4*)(Az + 12) = z;
        int pos = kb + lane;
        bool valid = pos < e1;
        int ps = valid ? pos : e0;
        float af = valid ? ab[ps] : 0.f;
        unsigned ahiu = bf16_rne(af);
        unsigned alou = bf16_rne(af - __uint_as_float(ahiu << 16));
        int rr = rowloc[ps];
        mOff[b][lane] = ssorted[ps] << 11;
        asm volatile("s_waitcnt lgkmcnt(0)" ::: "memory");
        A32[b][rr * 68 + lane] = ahiu | (alou << 16);
    };

    f32x4 acc0 = {}, acc1 = {};

    if (w == 0 && nk > 0) fill(0, e0);

    for (int i = 0; i < nk; ++i) {
        __syncthreads();
        const int b = i & 1;
        if (w == 0 && i + 1 < nk) fill(b ^ 1, e0 + (i + 1) * 64);

        const int mb = q * 8;
        int4 o0 = *(const int4*)&mOff[b][mb];
        int4 o1 = *(const int4*)&mOff[b][mb + 4];
        int4 o2 = *(const int4*)&mOff[b][32 + mb];
        int4 o3 = *(const int4*)&mOff[b][32 + mb + 4];
        int oo[16] = {o0.x, o0.y, o0.z, o0.w, o1.x, o1.y, o1.z, o1.w,
                      o2.x, o2.y, o2.z, o2.w, o3.x, o3.y, o3.z, o3.w};

        unsigned gld[16];
#pragma unroll
        for (int j = 0; j < 16; j++)
            gld[j] = *(const unsigned*)(hbase + (unsigned)(oo[j] + lanebyte));

        const unsigned* Ar = &A32[b][cl * 68 + mb];
        uint4 a0 = *(const uint4*)(Ar);
        uint4 a1 = *(const uint4*)(Ar + 4);
        uint4 a2 = *(const uint4*)(Ar + 32);
        uint4 a3 = *(const uint4*)(Ar + 36);
        unsigned aw[16] = {a0.x, a0.y, a0.z, a0.w, a1.x, a1.y, a1.z, a1.w,
                           a2.x, a2.y, a2.z, a2.w, a3.x, a3.y, a3.z, a3.w};

        union { unsigned u[4]; bf16x8 v; } ahi0, alo0, ahi1, alo1, b00, b10, b01, b11;
#pragma unroll
        for (int r = 0; r < 4; r++) {
            ahi0.u[r] = __builtin_amdgcn_perm(aw[2 * r + 1], aw[2 * r], 0x05040100u);
            alo0.u[r] = __builtin_amdgcn_perm(aw[2 * r + 1], aw[2 * r], 0x07060302u);
            ahi1.u[r] = __builtin_amdgcn_perm(aw[8 + 2 * r + 1], aw[8 + 2 * r], 0x05040100u);
            alo1.u[r] = __builtin_amdgcn_perm(aw[8 + 2 * r + 1], aw[8 + 2 * r], 0x07060302u);
            b00.u[r] = __builtin_amdgcn_perm(gld[2 * r + 1], gld[2 * r], 0x05040100u);
            b10.u[r] = __builtin_amdgcn_perm(gld[2 * r + 1], gld[2 * r], 0x07060302u);
            b01.u[r] = __builtin_amdgcn_perm(gld[8 + 2 * r + 1], gld[8 + 2 * r], 0x05040100u);
            b11.u[r] = __builtin_amdgcn_perm(gld[8 + 2 * r + 1], gld[8 + 2 * r], 0x07060302u);
        }

        acc0 = __builtin_amdgcn_mfma_f32_16x16x32_bf16(ahi0.v, b00.v, acc0, 0, 0, 0);
        acc0 = __builtin_amdgcn_mfma_f32_16x16x32_bf16(alo0.v, b00.v, acc0, 0, 0, 0);
        acc1 = __builtin_amdgcn_mfma_f32_16x16x32_bf16(ahi0.v, b10.v, acc1, 0, 0, 0);
        acc1 = __builtin_amdgcn_mfma_f32_16x16x32_bf16(alo0.v, b10.v, acc1, 0, 0, 0);
        acc0 = __builtin_amdgcn_mfma_f32_16x16x32_bf16(ahi1.v, b01.v, acc0, 0, 0, 0);
        acc0 = __builtin_amdgcn_mfma_f32_16x16x32_bf16(alo1.v, b01.v, acc0, 0, 0, 0);
        acc1 = __builtin_amdgcn_mfma_f32_16x16x32_bf16(ahi1.v, b11.v, acc1, 0, 0, 0);
        acc1 = __builtin_amdgcn_mfma_f32_16x16x32_bf16(alo1.v, b11.v, acc1, 0, 0, 0);
    }

    {
        int chbase = w * 32 + 2 * cl;
        float bv0 = bias[hh * C1 + chbase];
        float bv1 = bias[hh * C1 + chbase + 1];
#pragma unroll
        for (int r = 0; r < 4; r++) {
            int d = d0 + q * 4 + r;
            if (d >= N) continue;
            float v0 = acc0[r] + bv0;
            float v1 = acc1[r] + bv1;
            v0 = v0 > 0.f ? v0 : expm1f(v0);
            v1 = v1 > 0.f ? v1 : expm1f(v1);
            unsigned hi, lo;
            split2(v0, v1, hi, lo);
            size_t idx = (size_t)d * HC1 + hh * C1 + chbase;  // even
            ((unsigned*)outHi)[idx >> 1] = hi;
            ((unsigned*)outLo)[idx >> 1] = lo;
        }
    }
}

// ---------------- aggregation: one wave per (dst, head) (layer 2) ----------------

template<int H, bool SPLITOUT>
__global__ __launch_bounds__(256) void agg_bf(const unsigned* __restrict__ hbf,
                                              const float* __restrict__ ssrc,
                                              const float* __restrict__ sdst,
                                              const int* __restrict__ start,
                                              const int* __restrict__ ssorted,
                                              const float* __restrict__ bias,
                                              float* __restrict__ out,
                                              unsigned* __restrict__ outHi,
                                              unsigned* __restrict__ outLo, int N) {
    int hh, grp;
    if (H == 8) { hh = blockIdx.x & 7; grp = blockIdx.x >> 3; }
    else        { hh = 0;              grp = blockIdx.x; }
    int wid = threadIdx.x >> 6, lane = threadIdx.x & 63;
    int d = grp * 4 + wid;
    if (d >= N) return;
    const int g = lane >> 4, p = lane & 15;
    int s0 = start[d];
    int ne = start[d + 1] - s0;
    float sd = sdst[d * H + hh];

    const unsigned* hlane = hbf + hh * 64 + p * 4;
    const int rowstride = H * 64;

    int src0 = 0; float v0 = -1e30f;
    if (lane < ne) { src0 = ssorted[s0 + lane]; v0 = lrelu(ssrc[src0 * H + hh] + sd); }
    float m = v0;
    for (int e = lane + 64; e < ne; e += 64)
        m = fmaxf(m, lrelu(ssrc[ssorted[s0 + e] * H + hh] + sd));
    for (int o = 32; o; o >>= 1) m = fmaxf(m, __shfl_xor(m, o));

    float p0 = (lane < ne) ? __expf(v0 - m) : 0.f;
    float ssum = p0;
    for (int e = lane + 64; e < ne; e += 64)
        ssum += __expf(lrelu(ssrc[ssorted[s0 + e] * H + hh] + sd) - m);
    for (int o = 32; o; o >>= 1) ssum += __shfl_xor(ssum, o);
    float inv = 1.f / ssum;

    float acc[8] = {};
    for (int base = 0; base < ne; base += 64) {
        int srcr; float al;
        if (base == 0) { srcr = src0; al = p0 * inv; }
        else {
            srcr = 0; al = 0.f;
            int e = base + lane;
            if (e < ne) {
                srcr = ssorted[s0 + e];
                al = __expf(lrelu(ssrc[srcr * H + hh] + sd) - m) * inv;
            }
        }
        int cnt = min(64, ne - base);
        for (int e2 = 0; e2 < cnt; e2 += 4) {
            float a = __shfl(al, e2 + g);
            int sr = __shfl(srcr, e2 + g);
            uint4 u = *(const uint4*)(hlane + (size_t)sr * rowstride);
            acc[0] += a * __uint_as_float(u.x << 16);
            acc[1] += a * __uint_as_float(u.x & 0xffff0000u);
            acc[2] += a * __uint_as_float(u.y << 16);
            acc[3] += a * __uint_as_float(u.y & 0xffff0000u);
            acc[4] += a * __uint_as_float(u.z << 16);
            acc[5] += a * __uint_as_float(u.z & 0xffff0000u);
            acc[6] += a * __uint_as_float(u.w << 16);
            acc[7] += a * __uint_as_float(u.w & 0xffff0000u);
        }
    }

#pragma unroll
    for (int i = 0; i < 8; i++) {
        acc[i] += __shfl_xor(acc[i], 16);
        acc[i] += __shfl_xor(acc[i], 32);
    }

    float r0 = g == 0 ? acc[0] : g == 1 ? acc[2] : g == 2 ? acc[4] : acc[6];
    float r1 = g == 0 ? acc[1] : g == 1 ? acc[3] : g == 2 ? acc[5] : acc[7];
    int j = 4 * p + g;
    float2 bv = ((const float2*)bias)[hh * 64 + j];
    r0 += bv.x; r1 += bv.y;
    size_t idx = (size_t)d * (H * 64) + hh * 64 + j;
    if (SPLITOUT) {
        r0 = r0 > 0.f ? r0 : expm1f(r0);
        r1 = r1 > 0.f ? r1 : expm1f(r1);
        unsigned hi, lo;
        split2(r0, r1, hi, lo);
        outHi[idx] = hi;
        outLo[idx] = lo;
    } else {
        ((float2*)out)[idx] = make_float2(r0, r1);
    }
}

// ---------------- launch ----------------

extern "C" void kernel_launch(void* const* d_in, const int* in_sizes, int n_in,
                              void* d_out, int out_size, void* d_ws, size_t ws_size,
                              hipStream_t stream) {
    const float* x      = (const float*)d_in[0];
    const int*   ei     = (const int*)d_in[1];
    const float* W1     = (const float*)d_in[2];
    const float* a_src1 = (const float*)d_in[3];
    const float* a_dst1 = (const float*)d_in[4];
    const float* b1     = (const float*)d_in[5];
    const float* W2     = (const float*)d_in[6];
    const float* a_src2 = (const float*)d_in[7];
    const float* a_dst2 = (const float*)d_in[8];
    const float* b2     = (const float*)d_in[9];
    float* out = (float*)d_out;

    int E = in_sizes[1] / 2;
    int N = in_sizes[0] / F_IN;
    int ET = E + N;
    const int* esrc = ei;
    const int* edst = ei + E;

    char* ws = (char*)d_ws;
    size_t off = 0;
    auto alloc = [&](size_t bytes) -> char* {
        char* p = ws + off;
        off = (off + bytes + 255) & ~(size_t)255;
        return p;
    };
    u16* x_hi    = (u16*)alloc((size_t)N * F_IN * 2);
    u16* x_lo    = (u16*)alloc((size_t)N * F_IN * 2);
    u16* W1t_hi  = (u16*)alloc((size_t)F_IN * HC1 * 2);
    u16* W1t_lo  = (u16*)alloc((size_t)F_IN * HC1 * 2);
    u16* W2t_hi  = (u16*)alloc((size_t)HC1 * C2 * 2);
    u16* W2t_lo  = (u16*)alloc((size_t)HC1 * C2 * 2);
    u16* h1_bf   = (u16*)alloc((size_t)N * HC1 * 2);
    u16* h1a_hi  = (u16*)alloc((size_t)N * HC1 * 2);
    u16* h1a_lo  = (u16*)alloc((size_t)N * HC1 * 2);
    u16* h2_bf   = (u16*)alloc((size_t)N * C2 * 2);
    float* ss1   = (float*)alloc((size_t)N * H1 * 4);
    float* sd1   = (float*)alloc((size_t)N * H1 * 4);
    float* ss2   = (float*)alloc((size_t)N * 4);
    float* sd2   = (float*)alloc((size_t)N * 4);
    int* deg     = (int*)alloc((size_t)N * 4);
    int* startp  = (int*)alloc((size_t)(N + 1) * 4);
    int* cursor  = (int*)alloc((size_t)N * 4);
    int* ssorted = (int*)alloc((size_t)ET * 4);
    unsigned char* rowloc = (unsigned char*)alloc((size_t)ET);
    // alpha1 [H1][ET] fp32 (5.44 MB) aliases x_hi/x_lo (10.24 MB):
    // x_* are dead after gemm_mfma; softmax_edges1 runs strictly after it.
    float* alpha1 = (float*)x_hi;

    // all elementwise prep in one kernel (x split, deg=1, ss2/sd2 zero, W splits)
    split_all<<<(N * F_IN + 255) / 256, 256, 0, stream>>>(
        x, x_hi, x_lo, N * F_IN,
        W1, W1t_hi, W1t_lo, F_IN, HC1,
        W2, W2t_hi, W2t_lo, HC1, C2,
        deg, ss2, sd2, N);

    // edge sort by destination
    hist_kernel<<<(E + 255) / 256, 256, 0, stream>>>(edst, deg, E);
    scan_kernel<<<1, 1024, 0, stream>>>(deg, startp, cursor, N);
    scatter_kernel<<<(E + N + 255) / 256, 256, 0, stream>>>(esrc, edst, cursor, ssorted, rowloc, E, N);

    // layer 1 (scores fused into GEMM epilogue)
    gemm_mfma<<<dim3(HC1 / 128, (N + 127) / 128), 256, 0, stream>>>(
        x_hi, x_lo, W1t_hi, W1t_lo, h1_bf, N, HC1, F_IN, a_src1, a_dst1, ss1, sd1);
    softmax_edges1<<<(N * H1 + 15) / 16, 256, 0, stream>>>(
        ss1, sd1, startp, ssorted, alpha1, N, ET);
    agg_mfma1<<<((N + 15) / 16) * H1, 256, 0, stream>>>(
        h1_bf, alpha1, rowloc, startp, ssorted, b1, h1a_hi, h1a_lo, N, ET);

    // layer 2 (64x64 tiles, BK=64; scores2 fused into epilogue via atomicAdd)
    gemm_mfma64<<<dim3(C2 / 64, (N + 63) / 64), 256, 0, stream>>>(
        h1a_hi, h1a_lo, W2t_hi, W2t_lo, h2_bf, N, C2, HC1, a_src2, a_dst2, ss2, sd2);
    agg_bf<1, false><<<(N + 3) / 4, 256, 0, stream>>>(
        (const unsigned*)h2_bf, ss2, sd2, startp, ssorted, b2,
        out, nullptr, nullptr, N);
}

// Round 14
// 223.680 us; speedup vs baseline: 1.0464x; 1.0100x over previous
//
#include <hip/hip_runtime.h>
#include <math.h>

#define F_IN 256
#define H1 8
#define C1 128
#define HC1 1024
#define C2 128
#define SLOPE 0.2f

typedef unsigned short u16;
typedef __attribute__((ext_vector_type(8))) short bf16x8;
typedef __attribute__((ext_vector_type(4))) float f32x4;

// ---------------- helpers ----------------

__device__ __forceinline__ float lrelu(float v) { return v > 0.f ? v : SLOPE * v; }

__device__ __forceinline__ unsigned bf16_rne(float x) {
    unsigned u = __float_as_uint(x);
    u += 0x7fffu + ((u >> 16) & 1u);
    return u >> 16;
}

// split a,b into packed-bf16 hi pair and lo pair (lo = exact residual, rounded)
__device__ __forceinline__ void split2(float a, float b, unsigned& hi, unsigned& lo) {
    unsigned ha = bf16_rne(a), hb = bf16_rne(b);
    float fa = __uint_as_float(ha << 16), fb = __uint_as_float(hb << 16);
    hi = ha | (hb << 16);
    lo = bf16_rne(a - fa) | (bf16_rne(b - fb) << 16);
}

__device__ __forceinline__ void gload16(const u16* g, u16* l) {
    __builtin_amdgcn_global_load_lds(
        (const __attribute__((address_space(1))) unsigned*)g,
        (__attribute__((address_space(3))) unsigned*)l, 16, 0, 0);
}

// ---------------- edge sorting (counting sort by dst) ----------------

__global__ void hist_kernel(const int* __restrict__ dst, int* __restrict__ deg, int E) {
    int i = blockIdx.x * blockDim.x + threadIdx.x;
    if (i < E) atomicAdd(&deg[dst[i]], 1);
}

// wave-shuffle two-level scan: 3 barriers/chunk (was 20)
__global__ void scan_kernel(const int* __restrict__ deg, int* __restrict__ start,
                            int* __restrict__ cursor, int n) {
    __shared__ int wsum[16];
    __shared__ int wpre[16];
    __shared__ int ctot;
    const int tid = threadIdx.x;
    const int lane = tid & 63, wv = tid >> 6;
    int carry = 0;
    for (int base = 0; base < n; base += 1024) {
        int i = base + tid;
        int v = (i < n) ? deg[i] : 0;
        int x = v;  // inclusive wave scan
#pragma unroll
        for (int o = 1; o < 64; o <<= 1) {
            int y = __shfl_up(x, o);
            if (lane >= o) x += y;
        }
        if (lane == 63) wsum[wv] = x;
        __syncthreads();
        if (tid < 16) {
            int s = wsum[tid];
            int xx = s;
#pragma unroll
            for (int o = 1; o < 16; o <<= 1) {
                int y = __shfl_up(xx, o);
                if (tid >= o) xx += y;
            }
            wpre[tid] = xx - s;        // exclusive prefix of wave sums
            if (tid == 15) ctot = xx;  // chunk total
        }
        __syncthreads();
        int excl = carry + wpre[wv] + (x - v);
        if (i < n) { start[i] = excl; cursor[i] = excl; }
        carry += ctot;
        __syncthreads();  // protect wsum/wpre/ctot for next chunk
    }
    if (tid == 0) start[n] = carry;
}

__global__ void scatter_kernel(const int* __restrict__ src, const int* __restrict__ dst,
                               int* __restrict__ cursor, int* __restrict__ ssorted,
                               unsigned char* __restrict__ rowloc,
                               int E, int N) {
    int i = blockIdx.x * blockDim.x + threadIdx.x;
    if (i < E) {
        int d = dst[i];
        int pos = atomicAdd(&cursor[d], 1);
        ssorted[pos] = src[i];
        rowloc[pos] = (unsigned char)(d & 15);
    } else if (i < E + N) {
        int d = i - E;
        int pos = atomicAdd(&cursor[d], 1);
        ssorted[pos] = d;
        rowloc[pos] = (unsigned char)(d & 15);
    }
}

// ---------------- all elementwise prep in ONE kernel ----------------
// x hi/lo split + deg=1 init + ss2/sd2 zero + W1/W2 transposed splits.
// All writes disjoint & order-free; hist (consumer of deg) runs after.

__global__ void split_all(const float* __restrict__ x, u16* __restrict__ xhi,
                          u16* __restrict__ xlo, int nx,
                          const float* __restrict__ W1, u16* __restrict__ w1hi,
                          u16* __restrict__ w1lo, int R1, int Cc1,
                          const float* __restrict__ W2, u16* __restrict__ w2hi,
                          u16* __restrict__ w2lo, int R2, int Cc2,
                          int* __restrict__ deg, float* __restrict__ z1,
                          float* __restrict__ z2, int N) {
    int i = blockIdx.x * blockDim.x + threadIdx.x;
    if (i < N) { deg[i] = 1; z1[i] = 0.f; z2[i] = 0.f; }
    if (i < nx) {
        float v = x[i];
        unsigned h = bf16_rne(v);
        xhi[i] = (u16)h;
        xlo[i] = (u16)bf16_rne(v - __uint_as_float(h << 16));
    }
    int n1 = R1 * Cc1;
    if (i < n1) {
        int r = i / Cc1, c = i % Cc1;
        float v = W1[i];
        unsigned h = bf16_rne(v);
        w1hi[(size_t)c * R1 + r] = (u16)h;
        w1lo[(size_t)c * R1 + r] = (u16)bf16_rne(v - __uint_as_float(h << 16));
    } else if (i - n1 < R2 * Cc2) {
        int j = i - n1;
        int r = j / Cc2, c = j % Cc2;
        float v = W2[j];
        unsigned h = bf16_rne(v);
        w2hi[(size_t)c * R2 + r] = (u16)h;
        w2lo[(size_t)c * R2 + r] = (u16)bf16_rne(v - __uint_as_float(h << 16));
    }
}

// ---------------- split-bf16 MFMA GEMM, 128x128 tile, fused scores ----------
// C[M,N](bf16) = (Ahi+Alo)[M,K] @ (Bhi+Blo)^T[N,K], fp32 accumulate.
// Layer-1 only: col tile 128 = exactly one head -> the block computes that
// head's s_src/s_dst for its 128 rows in the epilogue (fp32 acc, lrow
// butterfly + 2KB LDS cross-wave combine). Replaces the scores1_bf kernel.

__global__ __launch_bounds__(256) void gemm_mfma(const u16* __restrict__ Ahi,
                                                 const u16* __restrict__ Alo,
                                                 const u16* __restrict__ Bhi,
                                                 const u16* __restrict__ Blo,
                                                 u16* __restrict__ Cbf,
                                                 int M, int N, int K,
                                                 const float* __restrict__ a_s,
                                                 const float* __restrict__ a_d,
                                                 float* __restrict__ ssrc,
                                                 float* __restrict__ sdst) {
    __shared__ u16 lds[16384];  // 4 tiles x [128][32] bf16 = 32 KB
    const int t = threadIdx.x;
    const int rbase = blockIdx.y * 128;
    const int cbase = blockIdx.x * 128;

    const int lane = t & 63;
    const int R0 = (t >> 7) << 6;
    const int C0 = ((t >> 6) & 1) << 6;
    const int lrow = lane & 15;
    const int kq = lane >> 4;

    f32x4 acc[4][4] = {};

    for (int k0 = 0; k0 < K; k0 += 32) {
#pragma unroll
        for (int i = 0; i < 2; i++) {
            int c = t + (i << 8);
            int row = c >> 2;
            int kc = (c & 3) << 3;
            int ar = min(rbase + row, M - 1);
            int br = cbase + row;
            gload16(Ahi + (size_t)ar * K + k0 + kc, &lds[c * 8]);
            gload16(Alo + (size_t)ar * K + k0 + kc, &lds[4096 + c * 8]);
            gload16(Bhi + (size_t)br * K + k0 + kc, &lds[8192 + c * 8]);
            gload16(Blo + (size_t)br * K + k0 + kc, &lds[12288 + c * 8]);
        }
        __syncthreads();

        bf16x8 ah[4], al[4], bh[4], bl[4];
#pragma unroll
        for (int m = 0; m < 4; m++) {
            int off = (R0 + (m << 4) + lrow) * 32 + (kq << 3);
            ah[m] = *(const bf16x8*)&lds[off];
            al[m] = *(const bf16x8*)&lds[4096 + off];
        }
#pragma unroll
        for (int n = 0; n < 4; n++) {
            int off = (C0 + (n << 4) + lrow) * 32 + (kq << 3);
            bh[n] = *(const bf16x8*)&lds[8192 + off];
            bl[n] = *(const bf16x8*)&lds[12288 + off];
        }
#pragma unroll
        for (int m = 0; m < 4; m++)
#pragma unroll
            for (int n = 0; n < 4; n++) {
                acc[m][n] = __builtin_amdgcn_mfma_f32_16x16x32_bf16(ah[m], bh[n], acc[m][n], 0, 0, 0);
                acc[m][n] = __builtin_amdgcn_mfma_f32_16x16x32_bf16(ah[m], bl[n], acc[m][n], 0, 0, 0);
                acc[m][n] = __builtin_amdgcn_mfma_f32_16x16x32_bf16(al[m], bh[n], acc[m][n], 0, 0, 0);
            }
        __syncthreads();
    }

    // C store
#pragma unroll
    for (int m = 0; m < 4; m++)
#pragma unroll
        for (int n = 0; n < 4; n++) {
            int col = cbase + C0 + (n << 4) + lrow;
#pragma unroll
            for (int r = 0; r < 4; r++) {
                int row = rbase + R0 + (m << 4) + kq * 4 + r;
                if (row < M) Cbf[(size_t)row * N + col] = (u16)bf16_rne(acc[m][n][r]);
            }
        }

    // fused scores for head = blockIdx.x (staging LDS is free after the loop)
    {
        float* fl = (float*)lds;     // sS = fl[0..255], sD = fl[256..511]
        const int head = blockIdx.x;
        const int c01 = (t >> 6) & 1;
        float asv[4], adv[4];
#pragma unroll
        for (int n = 0; n < 4; n++) {
            int col = head * 128 + C0 + (n << 4) + lrow;
            asv[n] = a_s[col];
            adv[n] = a_d[col];
        }
#pragma unroll
        for (int m = 0; m < 4; m++)
#pragma unroll
            for (int r = 0; r < 4; r++) {
                float vs = 0.f, vd = 0.f;
#pragma unroll
                for (int n = 0; n < 4; n++) {
                    float h = acc[m][n][r];
                    vs += asv[n] * h;
                    vd += adv[n] * h;
                }
#pragma unroll
                for (int o = 1; o < 16; o <<= 1) {  // reduce over lrow (16 lanes)
                    vs += __shfl_xor(vs, o);
                    vd += __shfl_xor(vd, o);
                }
                if (lrow == 0) {
                    int lr = R0 + (m << 4) + kq * 4 + r;
                    fl[c01 * 128 + lr] = vs;
                    fl[256 + c01 * 128 + lr] = vd;
                }
            }
        __syncthreads();
        if (t < 128) {
            int row = rbase + t;
            if (row < M) {
                ssrc[row * H1 + head] = fl[t] + fl[128 + t];
                sdst[row * H1 + head] = fl[256 + t] + fl[384 + t];
            }
        }
    }
}

// ---------------- split-bf16 MFMA GEMM, 64x64 tile, BK=64, fused scores2 ----
// Two [64][32] sub-tiles per operand per iteration -> 16 K-iterations,
// 24 MFMAs per barrier pair.  [verified passing, rounds 6-9]
// Layer-2 scores fused (r8 pattern): per-row partial over this block's 64
// cols from fp32 acc, lrow butterfly + LDS combine, then atomicAdd into
// ss2/sd2 (2 commutative adds onto exact 0 -> deterministic).

__global__ __launch_bounds__(256) void gemm_mfma64(const u16* __restrict__ Ahi,
                                                   const u16* __restrict__ Alo,
                                                   const u16* __restrict__ Bhi,
                                                   const u16* __restrict__ Blo,
                                                   u16* __restrict__ Cbf,
                                                   int M, int N, int K,
                                                   const float* __restrict__ a_s,
                                                   const float* __restrict__ a_d,
                                                   float* __restrict__ ssrc,
                                                   float* __restrict__ sdst) {
    __shared__ u16 lds[16384];  // 4 operands x [2 ksub][64][32] bf16 = 32 KB
    const int t = threadIdx.x;
    const int rbase = blockIdx.y * 64;
    const int cbase = blockIdx.x * 64;

    const int lane = t & 63;
    const int w = t >> 6;
    const int R0 = (w >> 1) << 5;   // 0 / 32
    const int C0 = (w & 1) << 5;    // 0 / 32
    const int lrow = lane & 15;
    const int kq = lane >> 4;

    f32x4 acc[2][2] = {};

    for (int k0 = 0; k0 < K; k0 += 64) {
        {
            int row = (w << 4) + (lane >> 2);
            int kcc = (lane & 3) << 3;
            int ar = min(rbase + row, M - 1);
            int br = cbase + row;
            const size_t ga = (size_t)ar * K + k0 + kcc;
            const size_t gb = (size_t)br * K + k0 + kcc;
            const int ldo = row * 32 + kcc;
#pragma unroll
            for (int s2 = 0; s2 < 2; s2++) {
                gload16(Ahi + ga + s2 * 32, &lds[s2 * 2048 + ldo]);
                gload16(Alo + ga + s2 * 32, &lds[4096 + s2 * 2048 + ldo]);
                gload16(Bhi + gb + s2 * 32, &lds[8192 + s2 * 2048 + ldo]);
                gload16(Blo + gb + s2 * 32, &lds[12288 + s2 * 2048 + ldo]);
            }
        }
        __syncthreads();

#pragma unroll
        for (int s = 0; s < 2; s++) {
            bf16x8 ah[2], al[2], bh[2], bl[2];
#pragma unroll
            for (int m = 0; m < 2; m++) {
                int off = s * 2048 + (R0 + (m << 4) + lrow) * 32 + (kq << 3);
                ah[m] = *(const bf16x8*)&lds[off];
                al[m] = *(const bf16x8*)&lds[4096 + off];
            }
#pragma unroll
            for (int n = 0; n < 2; n++) {
                int off = s * 2048 + (C0 + (n << 4) + lrow) * 32 + (kq << 3);
                bh[n] = *(const bf16x8*)&lds[8192 + off];
                bl[n] = *(const bf16x8*)&lds[12288 + off];
            }
#pragma unroll
            for (int m = 0; m < 2; m++)
#pragma unroll
                for (int n = 0; n < 2; n++) {
                    acc[m][n] = __builtin_amdgcn_mfma_f32_16x16x32_bf16(ah[m], bh[n], acc[m][n], 0, 0, 0);
                    acc[m][n] = __builtin_amdgcn_mfma_f32_16x16x32_bf16(ah[m], bl[n], acc[m][n], 0, 0, 0);
                    acc[m][n] = __builtin_amdgcn_mfma_f32_16x16x32_bf16(al[m], bh[n], acc[m][n], 0, 0, 0);
                }
        }
        __syncthreads();
    }

#pragma unroll
    for (int m = 0; m < 2; m++)
#pragma unroll
        for (int n = 0; n < 2; n++) {
            int col = cbase + C0 + (n << 4) + lrow;
#pragma unroll
            for (int r = 0; r < 4; r++) {
                int row = rbase + R0 + (m << 4) + kq * 4 + r;
                if (row < M) Cbf[(size_t)row * N + col] = (u16)bf16_rne(acc[m][n][r]);
            }
        }

    // fused layer-2 scores: partial over this block's 64 cols -> atomicAdd
    {
        float* fl = (float*)lds;  // vs: fl[0..127], vd: fl[128..255]
        const int c01 = w & 1;
        float asv[2], adv[2];
#pragma unroll
        for (int n = 0; n < 2; n++) {
            int col = cbase + C0 + (n << 4) + lrow;
            asv[n] = a_s[col];
            adv[n] = a_d[col];
        }
#pragma unroll
        for (int m = 0; m < 2; m++)
#pragma unroll
            for (int r = 0; r < 4; r++) {
                float vs = asv[0] * acc[m][0][r] + asv[1] * acc[m][1][r];
                float vd = adv[0] * acc[m][0][r] + adv[1] * acc[m][1][r];
#pragma unroll
                for (int o = 1; o < 16; o <<= 1) {
                    vs += __shfl_xor(vs, o);
                    vd += __shfl_xor(vd, o);
                }
                if (lrow == 0) {
                    int lr = R0 + (m << 4) + kq * 4 + r;  // 0..63
                    fl[c01 * 64 + lr] = vs;
                    fl[128 + c01 * 64 + lr] = vd;
                }
            }
        __syncthreads();
        if (t < 64) {
            int row = rbase + t;
            if (row < M) {
                atomicAdd(&ssrc[row], fl[t] + fl[64 + t]);
                atomicAdd(&sdst[row], fl[128 + t] + fl[192 + t]);
            }
        }
    }
}

// ---------------- layer-1 edge softmax: per-edge alpha (fp32) ----------------
// 16-lane group per (d, h) task; 4 tasks/wave, 16 tasks/block.
// r14: two cached register slots per lane (e = p, p+16; covers ne <= 32,
// ~99.98% of Poisson(16)-degree dsts) -> 1 gather + 1 exp per edge instead
// of 3 gathers. Tail (e >= 32) keeps the original recompute path.
// NOTE (round 6 lesson): fusing this into agg_mfma1 puts the alpha gather+exp
// on the producer wave's serial fill path -> +13us. Keep it separate.

__global__ __launch_bounds__(256) void softmax_edges1(
    const float* __restrict__ ssrc, const float* __restrict__ sdst,
    const int* __restrict__ start, const int* __restrict__ ssorted,
    float* __restrict__ alphab, int N, int ET) {
    int lane = threadIdx.x & 63;
    int p = lane & 15, g = lane >> 4;
    int task = (blockIdx.x * 4 + (threadIdx.x >> 6)) * 4 + g;
    if (task >= N * H1) return;
    int d = task >> 3, hh = task & 7;
    int s0 = start[d], ne = start[d + 1] - s0;
    float sd = sdst[d * H1 + hh];
    float v0 = -1e30f, v1 = -1e30f;
    if (p < ne)      v0 = lrelu(ssrc[ssorted[s0 + p] * H1 + hh] + sd);
    if (p + 16 < ne) v1 = lrelu(ssrc[ssorted[s0 + p + 16] * H1 + hh] + sd);
    float m = fmaxf(v0, v1);
    for (int e = p + 32; e < ne; e += 16)
        m = fmaxf(m, lrelu(ssrc[ssorted[s0 + e] * H1 + hh] + sd));
    for (int o = 8; o; o >>= 1) m = fmaxf(m, __shfl_xor(m, o));
    float e0 = (p < ne) ? __expf(v0 - m) : 0.f;
    float e1 = (p + 16 < ne) ? __expf(v1 - m) : 0.f;
    float s = e0 + e1;
    for (int e = p + 32; e < ne; e += 16)
        s += __expf(lrelu(ssrc[ssorted[s0 + e] * H1 + hh] + sd) - m);
    for (int o = 8; o; o >>= 1) s += __shfl_xor(s, o);
    float inv = 1.f / s;
    float* ab = alphab + (size_t)hh * ET;
    if (p < ne)      ab[s0 + p] = e0 * inv;
    if (p + 16 < ne) ab[s0 + p + 16] = e1 * inv;
    for (int e = p + 32; e < ne; e += 16)
        ab[s0 + e] = __expf(lrelu(ssrc[ssorted[s0 + e] * H1 + hh] + sd) - m) * inv;
}

// ---------------- layer-1 aggregation via MFMA (segmented SpMM) ----------------
// Block = 16 consecutive dsts x 1 head; 4 waves; wave w owns interleaved
// channels ch = 32w + 2*cl + nn (nn in {0,1}) -> one dword gather per edge.
// A-tile in LDS: A32[row][k] = alpha_hi|alpha_lo<<16, built ONCE per chunk
// by wave 0 (zero + scatter) from the COALESCED alpha stream.
// CHUNK = 64 edges, double-buffered A/mOff -> one barrier per chunk.
// No atomics: block owns its 16 rows.  [r11 structure VERBATIM — r10/r12
// structure changes both regressed; only the ELU impl changed in r14]

__global__ __launch_bounds__(256) void agg_mfma1(
    const u16* __restrict__ hbf,               // [N][H1*C1] bf16
    const float* __restrict__ alphab,          // [H1][ET] fp32
    const unsigned char* __restrict__ rowloc,  // [ET] = dst & 15
    const int* __restrict__ start,
    const int* __restrict__ ssorted,
    const float* __restrict__ bias,            // [H1*C1]
    u16* __restrict__ outHi, u16* __restrict__ outLo,
    int N, int ET) {
    __shared__ unsigned A32[2][16 * 68];  // 2 x 4.25 KB, padded stride
    __shared__ int mOff[2][64];           // src row byte offsets (src * 2048)

    const int hh = blockIdx.x & 7;  // head -> XCD locality
    const int g = blockIdx.x >> 3;
    const int t = threadIdx.x;
    const int w = t >> 6;
    const int lane = t & 63;
    const int cl = lane & 15, q = lane >> 4;

    const int d0 = g * 16;
    const int e0 = start[d0], e1 = start[min(d0 + 16, N)];
    const float* ab = alphab + (size_t)hh * ET;

    const int lanebyte = hh * 256 + w * 64 + 4 * cl;
    const char* hbase = (const char*)hbf;  // uniform base -> saddr loads

    const int nk = (e1 - e0 + 63) >> 6;

    auto fill = [&](int b, int kb) {
        unsigned* Az = &A32[b][(lane >> 2) * 68 + (lane & 3) * 16];
        uint4 z = {0u, 0u, 0u, 0u};
        *(uint4*)(Az) = z;
        *(uint4*)(Az + 4) = z;
        *(uint4*)(Az + 8) = z;
        *(uint4*)(Az + 12) = z;
        int pos = kb + lane;
        bool valid = pos < e1;
        int ps = valid ? pos : e0;
        float af = valid ? ab[ps] : 0.f;
        unsigned ahiu = bf16_rne(af);
        unsigned alou = bf16_rne(af - __uint_as_float(ahiu << 16));
        int rr = rowloc[ps];
        mOff[b][lane] = ssorted[ps] << 11;
        asm volatile("s_waitcnt lgkmcnt(0)" ::: "memory");
        A32[b][rr * 68 + lane] = ahiu | (alou << 16);
    };

    f32x4 acc0 = {}, acc1 = {};

    if (w == 0 && nk > 0) fill(0, e0);

    for (int i = 0; i < nk; ++i) {
        __syncthreads();
        const int b = i & 1;
        if (w == 0 && i + 1 < nk) fill(b ^ 1, e0 + (i + 1) * 64);

        const int mb = q * 8;
        int4 o0 = *(const int4*)&mOff[b][mb];
        int4 o1 = *(const int4*)&mOff[b][mb + 4];
        int4 o2 = *(const int4*)&mOff[b][32 + mb];
        int4 o3 = *(const int4*)&mOff[b][32 + mb + 4];
        int oo[16] = {o0.x, o0.y, o0.z, o0.w, o1.x, o1.y, o1.z, o1.w,
                      o2.x, o2.y, o2.z, o2.w, o3.x, o3.y, o3.z, o3.w};

        unsigned gld[16];
#pragma unroll
        for (int j = 0; j < 16; j++)
            gld[j] = *(const unsigned*)(hbase + (unsigned)(oo[j] + lanebyte));

        const unsigned* Ar = &A32[b][cl * 68 + mb];
        uint4 a0 = *(const uint4*)(Ar);
        uint4 a1 = *(const uint4*)(Ar + 4);
        uint4 a2 = *(const uint4*)(Ar + 32);
        uint4 a3 = *(const uint4*)(Ar + 36);
        unsigned aw[16] = {a0.x, a0.y, a0.z, a0.w, a1.x, a1.y, a1.z, a1.w,
                           a2.x, a2.y, a2.z, a2.w, a3.x, a3.y, a3.z, a3.w};

        union { unsigned u[4]; bf16x8 v; } ahi0, alo0, ahi1, alo1, b00, b10, b01, b11;
#pragma unroll
        for (int r = 0; r < 4; r++) {
            ahi0.u[r] = __builtin_amdgcn_perm(aw[2 * r + 1], aw[2 * r], 0x05040100u);
            alo0.u[r] = __builtin_amdgcn_perm(aw[2 * r + 1], aw[2 * r], 0x07060302u);
            ahi1.u[r] = __builtin_amdgcn_perm(aw[8 + 2 * r + 1], aw[8 + 2 * r], 0x05040100u);
            alo1.u[r] = __builtin_amdgcn_perm(aw[8 + 2 * r + 1], aw[8 + 2 * r], 0x07060302u);
            b00.u[r] = __builtin_amdgcn_perm(gld[2 * r + 1], gld[2 * r], 0x05040100u);
            b10.u[r] = __builtin_amdgcn_perm(gld[2 * r + 1], gld[2 * r], 0x07060302u);
            b01.u[r] = __builtin_amdgcn_perm(gld[8 + 2 * r + 1], gld[8 + 2 * r], 0x05040100u);
            b11.u[r] = __builtin_amdgcn_perm(gld[8 + 2 * r + 1], gld[8 + 2 * r], 0x07060302u);
        }

        acc0 = __builtin_amdgcn_mfma_f32_16x16x32_bf16(ahi0.v, b00.v, acc0, 0, 0, 0);
        acc0 = __builtin_amdgcn_mfma_f32_16x16x32_bf16(alo0.v, b00.v, acc0, 0, 0, 0);
        acc1 = __builtin_amdgcn_mfma_f32_16x16x32_bf16(ahi0.v, b10.v, acc1, 0, 0, 0);
        acc1 = __builtin_amdgcn_mfma_f32_16x16x32_bf16(alo0.v, b10.v, acc1, 0, 0, 0);
        acc0 = __builtin_amdgcn_mfma_f32_16x16x32_bf16(ahi1.v, b01.v, acc0, 0, 0, 0);
        acc0 = __builtin_amdgcn_mfma_f32_16x16x32_bf16(alo1.v, b01.v, acc0, 0, 0, 0);
        acc1 = __builtin_amdgcn_mfma_f32_16x16x32_bf16(ahi1.v, b11.v, acc1, 0, 0, 0);
        acc1 = __builtin_amdgcn_mfma_f32_16x16x32_bf16(alo1.v, b11.v, acc1, 0, 0, 0);
    }

    {
        int chbase = w * 32 + 2 * cl;
        float bv0 = bias[hh * C1 + chbase];
        float bv1 = bias[hh * C1 + chbase + 1];
#pragma unroll
        for (int r = 0; r < 4; r++) {
            int d = d0 + q * 4 + r;
            if (d >= N) continue;
            float v0 = acc0[r] + bv0;
            float v1 = acc1[r] + bv1;
            // ELU via hw exp (|err| <= ~6e-8, invisible under bf16 rounding)
            v0 = v0 > 0.f ? v0 : (__expf(v0) - 1.0f);
            v1 = v1 > 0.f ? v1 : (__expf(v1) - 1.0f);
            unsigned hi, lo;
            split2(v0, v1, hi, lo);
            size_t idx = (size_t)d * HC1 + hh * C1 + chbase;  // even
            ((unsigned*)outHi)[idx >> 1] = hi;
            ((unsigned*)outLo)[idx >> 1] = lo;
        }
    }
}

// ---------------- aggregation: one wave per (dst, head) (layer 2) ----------------

template<int H, bool SPLITOUT>
__global__ __launch_bounds__(256) void agg_bf(const unsigned* __restrict__ hbf,
                                              const float* __restrict__ ssrc,
                                              const float* __restrict__ sdst,
                                              const int* __restrict__ start,
                                              const int* __restrict__ ssorted,
                                              const float* __restrict__ bias,
                                              float* __restrict__ out,
                                              unsigned* __restrict__ outHi,
                                              unsigned* __restrict__ outLo, int N) {
    int hh, grp;
    if (H == 8) { hh = blockIdx.x & 7; grp = blockIdx.x >> 3; }
    else        { hh = 0;              grp = blockIdx.x; }
    int wid = threadIdx.x >> 6, lane = threadIdx.x & 63;
    int d = grp * 4 + wid;
    if (d >= N) return;
    const int g = lane >> 4, p = lane & 15;
    int s0 = start[d];
    int ne = start[d + 1] - s0;
    float sd = sdst[d * H + hh];

    const unsigned* hlane = hbf + hh * 64 + p * 4;
    const int rowstride = H * 64;

    int src0 = 0; float v0 = -1e30f;
    if (lane < ne) { src0 = ssorted[s0 + lane]; v0 = lrelu(ssrc[src0 * H + hh] + sd); }
    float m = v0;
    for (int e = lane + 64; e < ne; e += 64)
        m = fmaxf(m, lrelu(ssrc[ssorted[s0 + e] * H + hh] + sd));
    for (int o = 32; o; o >>= 1) m = fmaxf(m, __shfl_xor(m, o));

    float p0 = (lane < ne) ? __expf(v0 - m) : 0.f;
    float ssum = p0;
    for (int e = lane + 64; e < ne; e += 64)
        ssum += __expf(lrelu(ssrc[ssorted[s0 + e] * H + hh] + sd) - m);
    for (int o = 32; o; o >>= 1) ssum += __shfl_xor(ssum, o);
    float inv = 1.f / ssum;

    float acc[8] = {};
    for (int base = 0; base < ne; base += 64) {
        int srcr; float al;
        if (base == 0) { srcr = src0; al = p0 * inv; }
        else {
            srcr = 0; al = 0.f;
            int e = base + lane;
            if (e < ne) {
                srcr = ssorted[s0 + e];
                al = __expf(lrelu(ssrc[srcr * H + hh] + sd) - m) * inv;
            }
        }
        int cnt = min(64, ne - base);
        for (int e2 = 0; e2 < cnt; e2 += 4) {
            float a = __shfl(al, e2 + g);
            int sr = __shfl(srcr, e2 + g);
            uint4 u = *(const uint4*)(hlane + (size_t)sr * rowstride);
            acc[0] += a * __uint_as_float(u.x << 16);
            acc[1] += a * __uint_as_float(u.x & 0xffff0000u);
            acc[2] += a * __uint_as_float(u.y << 16);
            acc[3] += a * __uint_as_float(u.y & 0xffff0000u);
            acc[4] += a * __uint_as_float(u.z << 16);
            acc[5] += a * __uint_as_float(u.z & 0xffff0000u);
            acc[6] += a * __uint_as_float(u.w << 16);
            acc[7] += a * __uint_as_float(u.w & 0xffff0000u);
        }
    }

#pragma unroll
    for (int i = 0; i < 8; i++) {
        acc[i] += __shfl_xor(acc[i], 16);
        acc[i] += __shfl_xor(acc[i], 32);
    }

    float r0 = g == 0 ? acc[0] : g == 1 ? acc[2] : g == 2 ? acc[4] : acc[6];
    float r1 = g == 0 ? acc[1] : g == 1 ? acc[3] : g == 2 ? acc[5] : acc[7];
    int j = 4 * p + g;
    float2 bv = ((const float2*)bias)[hh * 64 + j];
    r0 += bv.x; r1 += bv.y;
    size_t idx = (size_t)d * (H * 64) + hh * 64 + j;
    if (SPLITOUT) {
        r0 = r0 > 0.f ? r0 : expm1f(r0);
        r1 = r1 > 0.f ? r1 : expm1f(r1);
        unsigned hi, lo;
        split2(r0, r1, hi, lo);
        outHi[idx] = hi;
        outLo[idx] = lo;
    } else {
        ((float2*)out)[idx] = make_float2(r0, r1);
    }
}

// ---------------- launch ----------------

extern "C" void kernel_launch(void* const* d_in, const int* in_sizes, int n_in,
                              void* d_out, int out_size, void* d_ws, size_t ws_size,
                              hipStream_t stream) {
    const float* x      = (const float*)d_in[0];
    const int*   ei     = (const int*)d_in[1];
    const float* W1     = (const float*)d_in[2];
    const float* a_src1 = (const float*)d_in[3];
    const float* a_dst1 = (const float*)d_in[4];
    const float* b1     = (const float*)d_in[5];
    const float* W2     = (const float*)d_in[6];
    const float* a_src2 = (const float*)d_in[7];
    const float* a_dst2 = (const float*)d_in[8];
    const float* b2     = (const float*)d_in[9];
    float* out = (float*)d_out;

    int E = in_sizes[1] / 2;
    int N = in_sizes[0] / F_IN;
    int ET = E + N;
    const int* esrc = ei;
    const int* edst = ei + E;

    char* ws = (char*)d_ws;
    size_t off = 0;
    auto alloc = [&](size_t bytes) -> char* {
        char* p = ws + off;
        off = (off + bytes + 255) & ~(size_t)255;
        return p;
    };
    u16* x_hi    = (u16*)alloc((size_t)N * F_IN * 2);
    u16* x_lo    = (u16*)alloc((size_t)N * F_IN * 2);
    u16* W1t_hi  = (u16*)alloc((size_t)F_IN * HC1 * 2);
    u16* W1t_lo  = (u16*)alloc((size_t)F_IN * HC1 * 2);
    u16* W2t_hi  = (u16*)alloc((size_t)HC1 * C2 * 2);
    u16* W2t_lo  = (u16*)alloc((size_t)HC1 * C2 * 2);
    u16* h1_bf   = (u16*)alloc((size_t)N * HC1 * 2);
    u16* h1a_hi  = (u16*)alloc((size_t)N * HC1 * 2);
    u16* h1a_lo  = (u16*)alloc((size_t)N * HC1 * 2);
    u16* h2_bf   = (u16*)alloc((size_t)N * C2 * 2);
    float* ss1   = (float*)alloc((size_t)N * H1 * 4);
    float* sd1   = (float*)alloc((size_t)N * H1 * 4);
    float* ss2   = (float*)alloc((size_t)N * 4);
    float* sd2   = (float*)alloc((size_t)N * 4);
    int* deg     = (int*)alloc((size_t)N * 4);
    int* startp  = (int*)alloc((size_t)(N + 1) * 4);
    int* cursor  = (int*)alloc((size_t)N * 4);
    int* ssorted = (int*)alloc((size_t)ET * 4);
    unsigned char* rowloc = (unsigned char*)alloc((size_t)ET);
    // alpha1 [H1][ET] fp32 (5.44 MB) aliases x_hi/x_lo (10.24 MB):
    // x_* are dead after gemm_mfma; softmax_edges1 runs strictly after it.
    float* alpha1 = (float*)x_hi;

    // all elementwise prep in one kernel (x split, deg=1, ss2/sd2 zero, W splits)
    split_all<<<(N * F_IN + 255) / 256, 256, 0, stream>>>(
        x, x_hi, x_lo, N * F_IN,
        W1, W1t_hi, W1t_lo, F_IN, HC1,
        W2, W2t_hi, W2t_lo, HC1, C2,
        deg, ss2, sd2, N);

    // edge sort by destination
    hist_kernel<<<(E + 255) / 256, 256, 0, stream>>>(edst, deg, E);
    scan_kernel<<<1, 1024, 0, stream>>>(deg, startp, cursor, N);
    scatter_kernel<<<(E + N + 255) / 256, 256, 0, stream>>>(esrc, edst, cursor, ssorted, rowloc, E, N);

    // layer 1 (scores fused into GEMM epilogue)
    gemm_mfma<<<dim3(HC1 / 128, (N + 127) / 128), 256, 0, stream>>>(
        x_hi, x_lo, W1t_hi, W1t_lo, h1_bf, N, HC1, F_IN, a_src1, a_dst1, ss1, sd1);
    softmax_edges1<<<(N * H1 + 15) / 16, 256, 0, stream>>>(
        ss1, sd1, startp, ssorted, alpha1, N, ET);
    agg_mfma1<<<((N + 15) / 16) * H1, 256, 0, stream>>>(
        h1_bf, alpha1, rowloc, startp, ssorted, b1, h1a_hi, h1a_lo, N, ET);

    // layer 2 (64x64 tiles, BK=64; scores2 fused into epilogue via atomicAdd)
    gemm_mfma64<<<dim3(C2 / 64, (N + 63) / 64), 256, 0, stream>>>(
        h1a_hi, h1a_lo, W2t_hi, W2t_lo, h2_bf, N, C2, HC1, a_src2, a_dst2, ss2, sd2);
    agg_bf<1, false><<<(N + 3) / 4, 256, 0, stream>>>(
        (const unsigned*)h2_bf, ss2, sd2, startp, ssorted, b2,
        out, nullptr, nullptr, N);
}